// Round 7
// baseline (390.259 us; speedup 1.0000x reference)
//
#include <hip/hip_runtime.h>

#define B_     64
#define DIM_   384
#define RES_   14
#define N_     196
#define HEADS_ 8
#define KD_    32
#define D_     128
#define DH_    1024
#define QK_    256
#define CH_    1536
#define EPS_   1e-5f
#define SCALE_ 0.17677669529663687f   // 32^-0.5

typedef unsigned short u16;
typedef unsigned int u32;
typedef short v8s __attribute__((ext_vector_type(8)));
typedef float v4f __attribute__((ext_vector_type(4)));
typedef u16  v4u __attribute__((ext_vector_type(4)));

static __device__ __forceinline__ u16 f2bf(float f) {
    unsigned int u = __builtin_bit_cast(unsigned int, f);
    u = (u + 0x7fffu + ((u >> 16) & 1u)) >> 16;
    return (u16)u;
}
static __device__ __forceinline__ float bf2f(u16 u) {
    unsigned int x = ((unsigned int)u) << 16;
    return __builtin_bit_cast(float, x);
}
static __device__ __forceinline__ u16 f2h(float f) {
    _Float16 h = (_Float16)f;
    return __builtin_bit_cast(u16, h);
}
static __device__ __forceinline__ float h2f(u16 u) {
    return (float)__builtin_bit_cast(_Float16, u);
}

// async global->LDS, 16B per lane; LDS dest = wave-uniform base + lane*16
static __device__ __forceinline__ void gload_lds16(const u16* g, u16* l) {
    __builtin_amdgcn_global_load_lds(
        (const __attribute__((address_space(1))) void*)g,
        (__attribute__((address_space(3))) void*)l, 16, 0, 0);
}

// workspace layout (u16 element offsets)
// GEMM operand images: [kstep][kquad(4)][row(128)][8] = 4096 elems (8KB)/kstep
#define WBI_OFF  0u          // Wb  image: 12 mtiles x 12 ksteps      (589824)
#define WPI_OFF  589824u     // wp  image: 3 mtiles x 32 ksteps       (393216)
#define QI_OFF   983040u     // qT  [B][8][256][32]                   (4194304)
#define KI_OFF   5177344u    // kT  [B][8][256][32]                   (4194304)
#define VI_OFF   9371648u    // v   image: [B][8] x 7 ksteps          (14680064)
#define PBI_OFF  24051712u   // P   image: [B][8][nt2] x 7 ksteps     (29360128)
#define VLOC_U16 53411840u   // vloc [B][1024][196] bf16              (12845056 u16)
#define TAIL_OFF 79101952u   // union: xI (6291456) / aoI (16777216)
#define TB_OFF   98770944u   // BN tables fp32[5888]
#define ABT_OFF  98782720u   // abT [196][8] fp32

// ---------------------------------------------------------------------------
// 128x128 MFMA GEMM core, operands pre-packed as LDS images.
// ---------------------------------------------------------------------------
static __device__ __forceinline__ void gemm_core_g(
    const u16* __restrict__ Aimg, const u16* __restrict__ Bimg,
    int ksteps, u16* sA, u16* sB, v4f acc[4][4], int tid)
{
    const int lane = tid & 63;
    const int w    = tid >> 6;
    const int wm   = (w & 1) * 64;
    const int wn   = (w >> 1) * 64;
    const int quad = lane >> 4;
    const int l16  = lane & 15;
    const int la   = lane * 8;
    const int c0   = w * 1024;   // wave's two 512-elem chunks

    for (int ks = 0; ks < ksteps; ks++) {
        const u16* ga = Aimg + ks * 4096 + la;
        const u16* gb = Bimg + ks * 4096 + la;
        gload_lds16(ga + c0,       sA + c0);
        gload_lds16(ga + c0 + 512, sA + c0 + 512);
        gload_lds16(gb + c0,       sB + c0);
        gload_lds16(gb + c0 + 512, sB + c0 + 512);
        __syncthreads();
        v8s af[4], bf[4];
        #pragma unroll
        for (int i = 0; i < 4; i++)
            af[i] = *(const v8s*)&sA[(quad * 128 + wm + i * 16 + l16) * 8];
        #pragma unroll
        for (int j = 0; j < 4; j++)
            bf[j] = *(const v8s*)&sB[(quad * 128 + wn + j * 16 + l16) * 8];
        #pragma unroll
        for (int i = 0; i < 4; i++)
            #pragma unroll
            for (int j = 0; j < 4; j++)
                acc[i][j] = __builtin_amdgcn_mfma_f32_16x16x32_bf16(af[i], bf[j], acc[i][j], 0, 0, 0);
        __syncthreads();
    }
}

// ---------------------------------------------------------------------------
// pack weights into tile images + abT + BN scale/shift tables
// ---------------------------------------------------------------------------
__global__ __launch_bounds__(256) void k_castW(
    const float* __restrict__ wq, const float* __restrict__ wk,
    const float* __restrict__ wv, const float* __restrict__ wp,
    const float* __restrict__ ab,
    const float* __restrict__ bq, const float* __restrict__ bnq,
    const float* __restrict__ bk, const float* __restrict__ bnk,
    const float* __restrict__ bv, const float* __restrict__ bnv,
    const float* __restrict__ bp, const float* __restrict__ bnp,
    const float* __restrict__ bvl, const float* __restrict__ bnvl,
    u16* __restrict__ WbI, u16* __restrict__ WpI,
    float* __restrict__ abT, float* __restrict__ TB)
{
    int i = blockIdx.x * 256 + threadIdx.x;
    if (i < 589824) {           // qkv weight image
        int mt = i / 49152, rem = i % 49152;
        int ks = rem >> 12, r2 = rem & 4095;
        int q = r2 >> 10, row = (r2 >> 3) & 127, e = r2 & 7;
        int c = mt * 128 + row, k = ks * 32 + q * 8 + e;
        float v = (c < 256) ? wq[c * 384 + k]
                : (c < 512) ? wk[(c - 256) * 384 + k]
                            : wv[(size_t)(c - 512) * 384 + k];
        WbI[i] = f2bf(v);
    } else if (i < 983040) {    // proj weight image
        int j = i - 589824;
        int mt = j >> 17, rem = j & 131071;
        int ks = rem >> 12, r2 = rem & 4095;
        int q = r2 >> 10, row = (r2 >> 3) & 127, e = r2 & 7;
        int p = mt * 128 + row, k = ks * 32 + q * 8 + e;
        WpI[j] = f2bf(wp[(size_t)p * 1024 + k]);
    } else if (i < 984608) {    // abT
        int j = i - 983040;
        abT[j] = ab[(j & 7) * N_ + (j >> 3)];
    } else if (i < 987552) {    // BN tables
        int j = i - 984608;
        if (j < 256) {
            int c = j;
            float s = bnq[c] * rsqrtf(bnq[768 + c] + EPS_);
            float t = (bq[c] - bnq[512 + c]) * s + bnq[256 + c];
            TB[c] = s * SCALE_; TB[256 + c] = t * SCALE_;
        } else if (j < 512) {
            int c = j - 256;
            float s = bnk[c] * rsqrtf(bnk[768 + c] + EPS_);
            float t = (bk[c] - bnk[512 + c]) * s + bnk[256 + c];
            TB[512 + c] = s; TB[768 + c] = t;
        } else if (j < 1536) {
            int c = j - 512;
            float s = bnv[c] * rsqrtf(bnv[3072 + c] + EPS_);
            float t = (bv[c] - bnv[2048 + c]) * s + bnv[1024 + c];
            TB[1024 + c] = s; TB[2048 + c] = t;
        } else if (j < 1920) {
            int c = j - 1536;
            float s = bnp[c] * rsqrtf(bnp[1152 + c] + EPS_);
            float t = (bp[c] - bnp[768 + c]) * s + bnp[384 + c];
            TB[3072 + c] = s; TB[3456 + c] = t;
        } else {
            int c = j - 1920;
            float s = bnvl[c] * rsqrtf(bnvl[3072 + c] + EPS_);
            float t = (bvl[c] - bnvl[2048 + c]) * s + bnvl[1024 + c];
            TB[3840 + c] = s; TB[4864 + c] = t;
        }
    }
}

// ---------------------------------------------------------------------------
// x [B,384,196] fp32 -> xI image [B][nt2][12 ksteps][4096] bf16 (n>=196 zero)
// ---------------------------------------------------------------------------
__global__ __launch_bounds__(256) void k_castX(
    const float* __restrict__ x, u16* __restrict__ xI)
{
    __shared__ float T[64][65];
    const int tid = threadIdx.x;
    const int n0 = blockIdx.x * 64;
    const int k0 = blockIdx.y * 64;
    const int b  = blockIdx.z;
    const int c = tid & 63, r4 = tid >> 6;
    #pragma unroll
    for (int i = 0; i < 16; i++) {
        int kr = i * 4 + r4;
        int gn = n0 + c;
        T[kr][c] = (gn < N_) ? x[((size_t)b * DIM_ + k0 + kr) * N_ + gn] : 0.f;
    }
    __syncthreads();
    #pragma unroll
    for (int it = 0; it < 16; it++) {
        int j = it * 256 + tid;
        int kk = j & 63, nn = j >> 6;
        int k = k0 + kk, n = n0 + nn;
        xI[(size_t)b * 98304 + (n >> 7) * 49152 + (k >> 5) * 4096
           + ((k >> 3) & 3) * 1024 + (n & 127) * 8 + (k & 7)] = f2bf(T[kk][nn]);
    }
}

// ---------------------------------------------------------------------------
// K1: QKV GEMM. Outputs: qI/kI [b][h][256][32] bf16 (q pre-scaled),
// vI image per (b,o), 7 ksteps (n>=196 zero).
// ---------------------------------------------------------------------------
__global__ __launch_bounds__(256) void k_qkv(
    const u16* __restrict__ WbI, const u16* __restrict__ xI,
    const float* __restrict__ TB,
    u16* __restrict__ qI, u16* __restrict__ kI, u16* __restrict__ vI)
{
    __shared__ u16 sA[4096];
    __shared__ u16 sB[4096];
    const int tid = threadIdx.x;
    const int nt = blockIdx.x;
    const int mt = blockIdx.y;
    const int b  = blockIdx.z;
    v4f acc[4][4] = {};
    gemm_core_g(WbI + (size_t)mt * 49152,
                xI + ((size_t)b * 2 + nt) * 49152, 12, sA, sB, acc, tid);

    const int lane = tid & 63, w = tid >> 6;
    const int wm = (w & 1) * 64, wn = (w >> 1) * 64;
    const int quad = lane >> 4, l16 = lane & 15;
    #pragma unroll
    for (int i = 0; i < 4; i++) {
        #pragma unroll
        for (int j = 0; j < 4; j++) {
            int gc = mt * 128 + wm + i * 16 + quad * 4;  // global channel base
            int n  = nt * 128 + wn + j * 16 + l16;       // token (0..255)
            v4f v = acc[i][j];
            if (gc < 256) {            // q
                v4f s = *(const v4f*)&TB[gc];
                v4f t = *(const v4f*)&TB[256 + gc];
                v4u u;
                #pragma unroll
                for (int r = 0; r < 4; r++) u[r] = f2bf(v[r] * s[r] + t[r]);
                *(v4u*)&qI[((size_t)(b * 8 + (gc >> 5)) * 256 + n) * 32 + (gc & 31)] = u;
            } else if (gc < 512) {     // k
                int c = gc - 256;
                v4f s = *(const v4f*)&TB[512 + c];
                v4f t = *(const v4f*)&TB[768 + c];
                v4u u;
                #pragma unroll
                for (int r = 0; r < 4; r++) u[r] = f2bf(v[r] * s[r] + t[r]);
                *(v4u*)&kI[((size_t)(b * 8 + (c >> 5)) * 256 + n) * 32 + (c & 31)] = u;
            } else {                   // v -> image (row = e, col = n as k-dim)
                int c = gc - 512;      // 0..1023
                if (n < 224) {
                    int o = c >> 7, e = c & 127;
                    u16* base = vI + ((size_t)(b * 8 + o) * 7 + (n >> 5)) * 4096
                                + ((n >> 3) & 3) * 1024 + (n & 7);
                    #pragma unroll
                    for (int r = 0; r < 4; r++) {
                        u16 outv = 0;
                        if (n < N_) outv = f2bf(v[r] * TB[1024 + c + r] + TB[2048 + c + r]);
                        base[(e + r) * 8] = outv;
                    }
                }
            }
        }
    }
}

// ---------------------------------------------------------------------------
// K2: depthwise 3x3 conv. Block = 64 channels of one (b,o).
// ---------------------------------------------------------------------------
__global__ __launch_bounds__(256) void k_dwconv(
    const u16* __restrict__ vI, const float* __restrict__ wvl,
    const float* __restrict__ TB, u16* __restrict__ vlocB)
{
    __shared__ u16 V[64 * 230];             // 29440 B
    const int tid = threadIdx.x;
    const int sub = blockIdx.x;             // 0..15: o = sub>>1, half = sub&1
    const int b   = blockIdx.y;
    const int o   = sub >> 1;
    const int e0  = (sub & 1) * 64;
    const u16* img = vI + (size_t)(b * 8 + o) * 28672;

    {
        const int quad = tid >> 6, l = tid & 63;
        #pragma unroll
        for (int i = 0; i < 7; i++) {
            v8s u = *(const v8s*)&img[i * 4096 + quad * 1024 + (e0 + l) * 8];
            const u32* ui = (const u32*)&u;
            int m0 = i * 32 + quad * 8;
            u32* dst = (u32*)&V[l * 230 + m0];
            #pragma unroll
            for (int c = 0; c < 4; c++) dst[c] = ui[c];
        }
    }
    __syncthreads();

    const int e = tid & 63, j = tid >> 6;
    const int cg = sub * 64 + e;
    const int y0 = j * 4;
    const int ny = (j == 3) ? 2 : 4;
    float wgt[9];
    #pragma unroll
    for (int k = 0; k < 9; k++) wgt[k] = wvl[cg * 9 + k];
    const float sc = TB[3840 + cg], sh = TB[4864 + cg];
    u32 po[4][7];

    for (int yi = 0; yi < ny; yi++) {
        int y = y0 + yi;
        float a[3][16];
        #pragma unroll
        for (int dy = 0; dy < 3; dy++) {
            int yy = y + dy - 1;
            a[dy][0] = 0.f; a[dy][15] = 0.f;
            if (yy < 0 || yy > 13) {
                #pragma unroll
                for (int x = 1; x < 15; x++) a[dy][x] = 0.f;
            } else {
                const u16* rp = &V[e * 230 + yy * 14];
                #pragma unroll
                for (int c4 = 0; c4 < 7; c4++) {
                    u32 u = *(const u32*)&rp[c4 * 2];
                    a[dy][1 + 2 * c4] = bf2f((u16)(u & 0xffffu));
                    a[dy][2 + 2 * c4] = bf2f((u16)(u >> 16));
                }
            }
        }
        #pragma unroll
        for (int xp = 0; xp < 7; xp++) {
            u32 pk = 0;
            #pragma unroll
            for (int half = 0; half < 2; half++) {
                int x = 2 * xp + half;
                float s = 0.f;
                #pragma unroll
                for (int dy = 0; dy < 3; dy++)
                    #pragma unroll
                    for (int kx = 0; kx < 3; kx++)
                        s += wgt[dy * 3 + kx] * a[dy][x + kx];
                u16 bv = f2bf(s * sc + sh);
                pk |= ((u32)bv) << (16 * half);
            }
            po[yi][xp] = pk;
        }
    }
    __syncthreads();

    for (int yi = 0; yi < ny; yi++) {
        u32* dst = (u32*)&V[e * 196 + (y0 + yi) * 14];
        #pragma unroll
        for (int xp = 0; xp < 7; xp++) dst[xp] = po[yi][xp];
    }
    __syncthreads();

    u16* gout = vlocB + ((size_t)b * DH_ + sub * 64) * N_;
    #pragma unroll
    for (int i = 0; i < 7; i++) {
        int g = i * 256 + tid;
        if (g < 1568)
            *(v8s*)&gout[g * 8] = *(const v8s*)&V[g * 8];
    }
}

// ---------------------------------------------------------------------------
// K3: FUSED attention: scores (MFMA, LDS-resident) + bias + TH1 + softmax
// (no max-sub; scores bounded) + TH2 -> P image. Block = (qtile16, b).
// ---------------------------------------------------------------------------
__global__ __launch_bounds__(256) void k_attn(
    const u16* __restrict__ qI, const u16* __restrict__ kI,
    const float* __restrict__ th1w, const float* __restrict__ th1b,
    const float* __restrict__ th2w, const float* __restrict__ th2b,
    const float* __restrict__ abT, const int* __restrict__ bidx,
    u16* __restrict__ PbI)
{
    __shared__ u16 Sl[8 * 16 * 228];   // [h][q][m], m padded to 228 -> 58368 B
    __shared__ float red[2][4][8];
    const int tid = threadIdx.x;
    const int w = tid >> 6, lane = tid & 63;
    const int quad = lane >> 4, l16 = lane & 15;
    const int qt = blockIdx.x, b = blockIdx.y;
    const int n0 = qt * 16;

    // phase A: S[h][q][m] via MFMA; wave w -> heads 2w, 2w+1
    #pragma unroll
    for (int hh = 0; hh < 2; hh++) {
        int h = w * 2 + hh;
        const u16* qb = qI + (size_t)(b * 8 + h) * 8192;
        const u16* kb = kI + (size_t)(b * 8 + h) * 8192;
        v8s a = *(const v8s*)&qb[(n0 + l16) * 32 + quad * 8];
        for (int mt = 0; mt < 13; mt++) {
            v8s bfr = *(const v8s*)&kb[(mt * 16 + l16) * 32 + quad * 8];
            v4f acc = {};
            acc = __builtin_amdgcn_mfma_f32_16x16x32_bf16(a, bfr, acc, 0, 0, 0);
            #pragma unroll
            for (int r = 0; r < 4; r++)
                Sl[h * 3648 + (quad * 4 + r) * 228 + mt * 16 + l16] = f2h(acc[r]);
        }
    }
    __syncthreads();

    // phase B: thread owns key m; loop over 16 queries
    const int m = tid;
    const bool act = (m < N_);
    for (int q = 0; q < 16; q++) {
        int n = n0 + q;
        float A[8];
        if (act && n < N_) {
            int idx = bidx[n * N_ + m];
            v4f ab0 = *(const v4f*)&abT[idx * 8];
            v4f ab1 = *(const v4f*)&abT[idx * 8 + 4];
            float S[8];
            #pragma unroll
            for (int h = 0; h < 8; h++)
                S[h] = h2f(Sl[h * 3648 + q * 228 + m]) + ((h < 4) ? ab0[h] : ab1[h - 4]);
            #pragma unroll
            for (int o = 0; o < 8; o++) {
                float a = th1b[o];
                #pragma unroll
                for (int h = 0; h < 8; h++) a += th1w[o * 8 + h] * S[h];
                A[o] = a;
            }
        } else {
            #pragma unroll
            for (int o = 0; o < 8; o++) A[o] = -1e30f;
        }
        float e[8];
        #pragma unroll
        for (int o = 0; o < 8; o++) e[o] = __expf(A[o]);
        #pragma unroll
        for (int o = 0; o < 8; o++) {
            float v = e[o];
            #pragma unroll
            for (int off = 32; off > 0; off >>= 1) v += __shfl_xor(v, off, 64);
            if (lane == 0) red[q & 1][w][o] = v;
        }
        __syncthreads();
        float sc[8];
        #pragma unroll
        for (int o = 0; o < 8; o++) {
            float sm = (red[q & 1][0][o] + red[q & 1][1][o])
                     + (red[q & 1][2][o] + red[q & 1][3][o]);
            sc[o] = e[o] / sm;
        }
        if (m < 224) {
            #pragma unroll
            for (int o = 0; o < 8; o++) {
                float p = th2b[o];
                #pragma unroll
                for (int h = 0; h < 8; h++) p += th2w[o * 8 + h] * sc[h];
                Sl[o * 3648 + q * 228 + m] = act ? f2bf(p) : (u16)0;
            }
        }
    }
    __syncthreads();

    // phase C: copy P -> global image, 256B contiguous chunks
    const int half = n0 >> 7;
    const int row0 = n0 & 127;
    const int q = lane >> 2, jj = lane & 3;
    for (int i = 0; i < 56; i++) {
        int ch = w * 56 + i;
        int o = ch / 28, rem = ch - o * 28;
        int ks = rem >> 2, kq = rem & 3;
        u32 val = *(const u32*)&Sl[o * 3648 + q * 228 + ks * 32 + kq * 8 + jj * 2];
        u16* dst = PbI + ((size_t)(b * 8 + o) * 2 + half) * 28672
                 + ks * 4096 + kq * 1024 + row0 * 8;
        *(u32*)&dst[lane * 2] = val;
    }
}

// ---------------------------------------------------------------------------
// K5: attn @ V (K=224, 7 ksteps) + v_local(bf16) + relu -> aoI image
// ---------------------------------------------------------------------------
__global__ __launch_bounds__(256) void k_av(
    const u16* __restrict__ vI, const u16* __restrict__ PbI,
    const u16* __restrict__ vlocB, u16* __restrict__ aoI)
{
    __shared__ u16 sA[4096];
    __shared__ u16 sB[4096];
    const int tid = threadIdx.x;
    const int nt = blockIdx.x;
    const int o  = blockIdx.y;
    const int b  = blockIdx.z;
    v4f acc[4][4] = {};
    gemm_core_g(vI + (size_t)(b * 8 + o) * 28672,
                PbI + ((size_t)(b * 8 + o) * 2 + nt) * 28672, 7, sA, sB, acc, tid);

    const int lane = tid & 63, w = tid >> 6;
    const int wm = (w & 1) * 64, wn = (w >> 1) * 64;
    const int quad = lane >> 4, l16 = lane & 15;
    #pragma unroll
    for (int i = 0; i < 4; i++) {
        #pragma unroll
        for (int j = 0; j < 4; j++) {
            int lr = wm + i * 16 + quad * 4;        // e base
            int c0 = o * 128 + lr;                  // global k-index base
            int n  = nt * 128 + wn + j * 16 + l16;  // token (0..255)
            v4u u;
            #pragma unroll
            for (int r = 0; r < 4; r++) {
                u16 outv = 0;
                if (n < N_) {
                    float val = acc[i][j][r] + bf2f(vlocB[((size_t)b * DH_ + c0 + r) * N_ + n]);
                    outv = f2bf(fmaxf(val, 0.f));
                }
                u[r] = outv;
            }
            *(v4u*)&aoI[((size_t)(b * 2 + nt) * 32 + (c0 >> 5)) * 4096
                        + ((c0 >> 3) & 3) * 1024 + (n & 127) * 8 + (c0 & 7)] = u;
        }
    }
}

// ---------------------------------------------------------------------------
// K6: projection GEMM (K=1024, 32 ksteps) + BN -> out fp32
// ---------------------------------------------------------------------------
__global__ __launch_bounds__(256) void k_proj(
    const u16* __restrict__ WpI, const u16* __restrict__ aoI,
    const float* __restrict__ TB, float* __restrict__ out)
{
    __shared__ u16 sA[4096];
    __shared__ u16 sB[4096];
    const int tid = threadIdx.x;
    const int nt = blockIdx.x;
    const int mt = blockIdx.y;
    const int b  = blockIdx.z;
    v4f acc[4][4] = {};
    gemm_core_g(WpI + (size_t)mt * 131072,
                aoI + (size_t)(b * 2 + nt) * 131072, 32, sA, sB, acc, tid);

    const int lane = tid & 63, w = tid >> 6;
    const int wm = (w & 1) * 64, wn = (w >> 1) * 64;
    const int quad = lane >> 4, l16 = lane & 15;
    #pragma unroll
    for (int i = 0; i < 4; i++) {
        #pragma unroll
        for (int j = 0; j < 4; j++) {
            int p0 = mt * 128 + wm + i * 16 + quad * 4;
            int n  = nt * 128 + wn + j * 16 + l16;
            if (n < N_) {
                v4f s = *(const v4f*)&TB[3072 + p0];
                v4f t = *(const v4f*)&TB[3456 + p0];
                #pragma unroll
                for (int r = 0; r < 4; r++)
                    out[((size_t)b * DIM_ + p0 + r) * N_ + n] = acc[i][j][r] * s[r] + t[r];
            }
        }
    }
}

// ---------------------------------------------------------------------------
extern "C" void kernel_launch(void* const* d_in, const int* in_sizes, int n_in,
                              void* d_out, int out_size, void* d_ws, size_t ws_size,
                              hipStream_t stream)
{
    const float* x    = (const float*)d_in[0];
    const float* wq   = (const float*)d_in[1];
    const float* bq   = (const float*)d_in[2];
    const float* bnq  = (const float*)d_in[3];
    const float* wk   = (const float*)d_in[4];
    const float* bk   = (const float*)d_in[5];
    const float* bnk  = (const float*)d_in[6];
    const float* wv   = (const float*)d_in[7];
    const float* bv   = (const float*)d_in[8];
    const float* bnv  = (const float*)d_in[9];
    const float* wvl  = (const float*)d_in[10];
    const float* bvl  = (const float*)d_in[11];
    const float* bnvl = (const float*)d_in[12];
    const float* th1w = (const float*)d_in[13];
    const float* th1b = (const float*)d_in[14];
    const float* th2w = (const float*)d_in[15];
    const float* th2b = (const float*)d_in[16];
    const float* wp   = (const float*)d_in[17];
    const float* bp   = (const float*)d_in[18];
    const float* bnp  = (const float*)d_in[19];
    const float* ab   = (const float*)d_in[20];
    const int*   bidx = (const int*)d_in[21];
    float* out = (float*)d_out;

    u16* wsb  = (u16*)d_ws;
    u16* WbI  = wsb + WBI_OFF;
    u16* WpI  = wsb + WPI_OFF;
    u16* qI   = wsb + QI_OFF;
    u16* kI   = wsb + KI_OFF;
    u16* vI   = wsb + VI_OFF;
    u16* PbI  = wsb + PBI_OFF;
    u16* vlocB = wsb + VLOC_U16;
    u16* xI   = wsb + TAIL_OFF;   // aliased: xI -> aoI (disjoint lifetimes)
    u16* aoI  = wsb + TAIL_OFF;
    float* TB  = (float*)(wsb + TB_OFF);
    float* abT = (float*)(wsb + ABT_OFF);

    k_castW<<<dim3(3859), 256, 0, stream>>>(wq, wk, wv, wp, ab,
                                            bq, bnq, bk, bnk, bv, bnv, bp, bnp, bvl, bnvl,
                                            WbI, WpI, abT, TB);
    k_castX<<<dim3(4, 6, B_), 256, 0, stream>>>(x, xI);
    k_qkv<<<dim3(2, 12, B_), 256, 0, stream>>>(WbI, xI, TB, qI, kI, vI);
    k_dwconv<<<dim3(16, B_), 256, 0, stream>>>(vI, wvl, TB, vlocB);
    k_attn<<<dim3(13, B_), 256, 0, stream>>>(qI, kI, th1w, th1b, th2w, th2b, abT, bidx, PbI);
    k_av<<<dim3(2, HEADS_, B_), 256, 0, stream>>>(vI, PbI, vlocB, aoI);
    k_proj<<<dim3(2, 3, B_), 256, 0, stream>>>(WpI, aoI, TB, out);
}

// Round 8
// 328.723 us; speedup vs baseline: 1.1872x; 1.1872x over previous
//
#include <hip/hip_runtime.h>

#define B_     64
#define DIM_   384
#define RES_   14
#define N_     196
#define HEADS_ 8
#define KD_    32
#define D_     128
#define DH_    1024
#define QK_    256
#define CH_    1536
#define EPS_   1e-5f
#define SCALE_ 0.17677669529663687f   // 32^-0.5

typedef unsigned short u16;
typedef unsigned int u32;
typedef short v8s __attribute__((ext_vector_type(8)));
typedef float v4f __attribute__((ext_vector_type(4)));
typedef u16  v4u __attribute__((ext_vector_type(4)));

static __device__ __forceinline__ u16 f2bf(float f) {
    unsigned int u = __builtin_bit_cast(unsigned int, f);
    u = (u + 0x7fffu + ((u >> 16) & 1u)) >> 16;
    return (u16)u;
}
static __device__ __forceinline__ float bf2f(u16 u) {
    unsigned int x = ((unsigned int)u) << 16;
    return __builtin_bit_cast(float, x);
}
static __device__ __forceinline__ u16 f2h(float f) {
    _Float16 h = (_Float16)f;
    return __builtin_bit_cast(u16, h);
}
static __device__ __forceinline__ float h2f(u16 u) {
    return (float)__builtin_bit_cast(_Float16, u);
}

// async global->LDS, 16B per lane; LDS dest = wave-uniform base + lane*16
static __device__ __forceinline__ void gload_lds16(const u16* g, u16* l) {
    __builtin_amdgcn_global_load_lds(
        (const __attribute__((address_space(1))) void*)g,
        (__attribute__((address_space(3))) void*)l, 16, 0, 0);
}

// workspace layout (u16 element offsets)
// GEMM operand images: [kstep][kquad(4)][row(128)][8] = 4096 elems (8KB)/kstep
#define WBI_OFF  0u          // Wb  image: 12 mtiles x 12 ksteps      (589824)
#define WPI_OFF  589824u     // wp  image: 3 mtiles x 32 ksteps       (393216)
#define QI_OFF   983040u     // qT  [B][8][256][32]                   (4194304)
#define KI_OFF   5177344u    // kT  [B][8][256][32]                   (4194304)
#define VI_OFF   9371648u    // v   image: [B][8] x 7 ksteps          (14680064)
#define PBI_OFF  24051712u   // P   image: [B][8][nt2] x 7 ksteps     (29360128)
#define VLOC_U16 53411840u   // vloc [B][1024][196] bf16              (12845056 u16)
#define TAIL_OFF 79101952u   // union: xI (6291456) / aoI (16777216)
#define TB_OFF   98770944u   // BN tables fp32[5888]
#define ABT_OFF  98782720u   // abT1 [196][8] fp32 (th1-folded bias)

// ---------------------------------------------------------------------------
// 128x128 MFMA GEMM core, operands pre-packed as LDS images.
// ---------------------------------------------------------------------------
static __device__ __forceinline__ void gemm_core_g(
    const u16* __restrict__ Aimg, const u16* __restrict__ Bimg,
    int ksteps, u16* sA, u16* sB, v4f acc[4][4], int tid)
{
    const int lane = tid & 63;
    const int w    = tid >> 6;
    const int wm   = (w & 1) * 64;
    const int wn   = (w >> 1) * 64;
    const int quad = lane >> 4;
    const int l16  = lane & 15;
    const int la   = lane * 8;
    const int c0   = w * 1024;   // wave's two 512-elem chunks

    for (int ks = 0; ks < ksteps; ks++) {
        const u16* ga = Aimg + ks * 4096 + la;
        const u16* gb = Bimg + ks * 4096 + la;
        gload_lds16(ga + c0,       sA + c0);
        gload_lds16(ga + c0 + 512, sA + c0 + 512);
        gload_lds16(gb + c0,       sB + c0);
        gload_lds16(gb + c0 + 512, sB + c0 + 512);
        __syncthreads();
        v8s af[4], bf[4];
        #pragma unroll
        for (int i = 0; i < 4; i++)
            af[i] = *(const v8s*)&sA[(quad * 128 + wm + i * 16 + l16) * 8];
        #pragma unroll
        for (int j = 0; j < 4; j++)
            bf[j] = *(const v8s*)&sB[(quad * 128 + wn + j * 16 + l16) * 8];
        #pragma unroll
        for (int i = 0; i < 4; i++)
            #pragma unroll
            for (int j = 0; j < 4; j++)
                acc[i][j] = __builtin_amdgcn_mfma_f32_16x16x32_bf16(af[i], bf[j], acc[i][j], 0, 0, 0);
        __syncthreads();
    }
}

// ---------------------------------------------------------------------------
// pack weights into tile images + abT1 (th1-folded bias) + BN tables
// ---------------------------------------------------------------------------
__global__ __launch_bounds__(256) void k_castW(
    const float* __restrict__ wq, const float* __restrict__ wk,
    const float* __restrict__ wv, const float* __restrict__ wp,
    const float* __restrict__ ab,
    const float* __restrict__ th1w, const float* __restrict__ th1b,
    const float* __restrict__ bq, const float* __restrict__ bnq,
    const float* __restrict__ bk, const float* __restrict__ bnk,
    const float* __restrict__ bv, const float* __restrict__ bnv,
    const float* __restrict__ bp, const float* __restrict__ bnp,
    const float* __restrict__ bvl, const float* __restrict__ bnvl,
    u16* __restrict__ WbI, u16* __restrict__ WpI,
    float* __restrict__ abT1, float* __restrict__ TB)
{
    int i = blockIdx.x * 256 + threadIdx.x;
    if (i < 589824) {           // qkv weight image
        int mt = i / 49152, rem = i % 49152;
        int ks = rem >> 12, r2 = rem & 4095;
        int q = r2 >> 10, row = (r2 >> 3) & 127, e = r2 & 7;
        int c = mt * 128 + row, k = ks * 32 + q * 8 + e;
        float v = (c < 256) ? wq[c * 384 + k]
                : (c < 512) ? wk[(c - 256) * 384 + k]
                            : wv[(size_t)(c - 512) * 384 + k];
        WbI[i] = f2bf(v);
    } else if (i < 983040) {    // proj weight image
        int j = i - 589824;
        int mt = j >> 17, rem = j & 131071;
        int ks = rem >> 12, r2 = rem & 4095;
        int q = r2 >> 10, row = (r2 >> 3) & 127, e = r2 & 7;
        int p = mt * 128 + row, k = ks * 32 + q * 8 + e;
        WpI[j] = f2bf(wp[(size_t)p * 1024 + k]);
    } else if (i < 984608) {    // abT1[idx][o] = th1b[o] + sum_h th1w[o][h]*ab[h][idx]
        int j = i - 983040;
        int idx = j >> 3, o = j & 7;
        float a = th1b[o];
        #pragma unroll
        for (int h = 0; h < 8; h++) a += th1w[o * 8 + h] * ab[h * N_ + idx];
        abT1[j] = a;
    } else if (i < 987552) {    // BN tables
        int j = i - 984608;
        if (j < 256) {
            int c = j;
            float s = bnq[c] * rsqrtf(bnq[768 + c] + EPS_);
            float t = (bq[c] - bnq[512 + c]) * s + bnq[256 + c];
            TB[c] = s * SCALE_; TB[256 + c] = t * SCALE_;
        } else if (j < 512) {
            int c = j - 256;
            float s = bnk[c] * rsqrtf(bnk[768 + c] + EPS_);
            float t = (bk[c] - bnk[512 + c]) * s + bnk[256 + c];
            TB[512 + c] = s; TB[768 + c] = t;
        } else if (j < 1536) {
            int c = j - 512;
            float s = bnv[c] * rsqrtf(bnv[3072 + c] + EPS_);
            float t = (bv[c] - bnv[2048 + c]) * s + bnv[1024 + c];
            TB[1024 + c] = s; TB[2048 + c] = t;
        } else if (j < 1920) {
            int c = j - 1536;
            float s = bnp[c] * rsqrtf(bnp[1152 + c] + EPS_);
            float t = (bp[c] - bnp[768 + c]) * s + bnp[384 + c];
            TB[3072 + c] = s; TB[3456 + c] = t;
        } else {
            int c = j - 1920;
            float s = bnvl[c] * rsqrtf(bnvl[3072 + c] + EPS_);
            float t = (bvl[c] - bnvl[2048 + c]) * s + bnvl[1024 + c];
            TB[3840 + c] = s; TB[4864 + c] = t;
        }
    }
}

// ---------------------------------------------------------------------------
// x [B,384,196] fp32 -> xI image [B][nt2][12 ksteps][4096] bf16 (n>=196 zero)
// ---------------------------------------------------------------------------
__global__ __launch_bounds__(256) void k_castX(
    const float* __restrict__ x, u16* __restrict__ xI)
{
    __shared__ float T[64][65];
    const int tid = threadIdx.x;
    const int n0 = blockIdx.x * 64;
    const int k0 = blockIdx.y * 64;
    const int b  = blockIdx.z;
    const int c = tid & 63, r4 = tid >> 6;
    #pragma unroll
    for (int i = 0; i < 16; i++) {
        int kr = i * 4 + r4;
        int gn = n0 + c;
        T[kr][c] = (gn < N_) ? x[((size_t)b * DIM_ + k0 + kr) * N_ + gn] : 0.f;
    }
    __syncthreads();
    #pragma unroll
    for (int it = 0; it < 16; it++) {
        int j = it * 256 + tid;
        int kk = j & 63, nn = j >> 6;
        int k = k0 + kk, n = n0 + nn;
        xI[(size_t)b * 98304 + (n >> 7) * 49152 + (k >> 5) * 4096
           + ((k >> 3) & 3) * 1024 + (n & 127) * 8 + (k & 7)] = f2bf(T[kk][nn]);
    }
}

// ---------------------------------------------------------------------------
// K1: QKV GEMM. Outputs: qI/kI [b][h][256][32] bf16 (q pre-scaled),
// vI image per (b,o), 7 ksteps (n>=196 zero).
// ---------------------------------------------------------------------------
__global__ __launch_bounds__(256) void k_qkv(
    const u16* __restrict__ WbI, const u16* __restrict__ xI,
    const float* __restrict__ TB,
    u16* __restrict__ qI, u16* __restrict__ kI, u16* __restrict__ vI)
{
    __shared__ u16 sA[4096];
    __shared__ u16 sB[4096];
    const int tid = threadIdx.x;
    const int nt = blockIdx.x;
    const int mt = blockIdx.y;
    const int b  = blockIdx.z;
    v4f acc[4][4] = {};
    gemm_core_g(WbI + (size_t)mt * 49152,
                xI + ((size_t)b * 2 + nt) * 49152, 12, sA, sB, acc, tid);

    const int lane = tid & 63, w = tid >> 6;
    const int wm = (w & 1) * 64, wn = (w >> 1) * 64;
    const int quad = lane >> 4, l16 = lane & 15;
    #pragma unroll
    for (int i = 0; i < 4; i++) {
        #pragma unroll
        for (int j = 0; j < 4; j++) {
            int gc = mt * 128 + wm + i * 16 + quad * 4;  // global channel base
            int n  = nt * 128 + wn + j * 16 + l16;       // token (0..255)
            v4f v = acc[i][j];
            if (gc < 256) {            // q
                v4f s = *(const v4f*)&TB[gc];
                v4f t = *(const v4f*)&TB[256 + gc];
                v4u u;
                #pragma unroll
                for (int r = 0; r < 4; r++) u[r] = f2bf(v[r] * s[r] + t[r]);
                *(v4u*)&qI[((size_t)(b * 8 + (gc >> 5)) * 256 + n) * 32 + (gc & 31)] = u;
            } else if (gc < 512) {     // k
                int c = gc - 256;
                v4f s = *(const v4f*)&TB[512 + c];
                v4f t = *(const v4f*)&TB[768 + c];
                v4u u;
                #pragma unroll
                for (int r = 0; r < 4; r++) u[r] = f2bf(v[r] * s[r] + t[r]);
                *(v4u*)&kI[((size_t)(b * 8 + (c >> 5)) * 256 + n) * 32 + (c & 31)] = u;
            } else {                   // v -> image (row = e, col = n as k-dim)
                int c = gc - 512;      // 0..1023
                if (n < 224) {
                    int o = c >> 7, e = c & 127;
                    u16* base = vI + ((size_t)(b * 8 + o) * 7 + (n >> 5)) * 4096
                                + ((n >> 3) & 3) * 1024 + (n & 7);
                    #pragma unroll
                    for (int r = 0; r < 4; r++) {
                        u16 outv = 0;
                        if (n < N_) outv = f2bf(v[r] * TB[1024 + c + r] + TB[2048 + c + r]);
                        base[(e + r) * 8] = outv;
                    }
                }
            }
        }
    }
}

// ---------------------------------------------------------------------------
// K2: depthwise 3x3 conv. Block = 64 channels of one (b,o).
// ---------------------------------------------------------------------------
__global__ __launch_bounds__(256) void k_dwconv(
    const u16* __restrict__ vI, const float* __restrict__ wvl,
    const float* __restrict__ TB, u16* __restrict__ vlocB)
{
    __shared__ u16 V[64 * 230];             // 29440 B
    const int tid = threadIdx.x;
    const int sub = blockIdx.x;             // 0..15: o = sub>>1, half = sub&1
    const int b   = blockIdx.y;
    const int o   = sub >> 1;
    const int e0  = (sub & 1) * 64;
    const u16* img = vI + (size_t)(b * 8 + o) * 28672;

    {
        const int quad = tid >> 6, l = tid & 63;
        #pragma unroll
        for (int i = 0; i < 7; i++) {
            v8s u = *(const v8s*)&img[i * 4096 + quad * 1024 + (e0 + l) * 8];
            const u32* ui = (const u32*)&u;
            int m0 = i * 32 + quad * 8;
            u32* dst = (u32*)&V[l * 230 + m0];
            #pragma unroll
            for (int c = 0; c < 4; c++) dst[c] = ui[c];
        }
    }
    __syncthreads();

    const int e = tid & 63, j = tid >> 6;
    const int cg = sub * 64 + e;
    const int y0 = j * 4;
    const int ny = (j == 3) ? 2 : 4;
    float wgt[9];
    #pragma unroll
    for (int k = 0; k < 9; k++) wgt[k] = wvl[cg * 9 + k];
    const float sc = TB[3840 + cg], sh = TB[4864 + cg];
    u32 po[4][7];

    for (int yi = 0; yi < ny; yi++) {
        int y = y0 + yi;
        float a[3][16];
        #pragma unroll
        for (int dy = 0; dy < 3; dy++) {
            int yy = y + dy - 1;
            a[dy][0] = 0.f; a[dy][15] = 0.f;
            if (yy < 0 || yy > 13) {
                #pragma unroll
                for (int x = 1; x < 15; x++) a[dy][x] = 0.f;
            } else {
                const u16* rp = &V[e * 230 + yy * 14];
                #pragma unroll
                for (int c4 = 0; c4 < 7; c4++) {
                    u32 u = *(const u32*)&rp[c4 * 2];
                    a[dy][1 + 2 * c4] = bf2f((u16)(u & 0xffffu));
                    a[dy][2 + 2 * c4] = bf2f((u16)(u >> 16));
                }
            }
        }
        #pragma unroll
        for (int xp = 0; xp < 7; xp++) {
            u32 pk = 0;
            #pragma unroll
            for (int half = 0; half < 2; half++) {
                int x = 2 * xp + half;
                float s = 0.f;
                #pragma unroll
                for (int dy = 0; dy < 3; dy++)
                    #pragma unroll
                    for (int kx = 0; kx < 3; kx++)
                        s += wgt[dy * 3 + kx] * a[dy][x + kx];
                u16 bv = f2bf(s * sc + sh);
                pk |= ((u32)bv) << (16 * half);
            }
            po[yi][xp] = pk;
        }
    }
    __syncthreads();

    for (int yi = 0; yi < ny; yi++) {
        u32* dst = (u32*)&V[e * 196 + (y0 + yi) * 14];
        #pragma unroll
        for (int xp = 0; xp < 7; xp++) dst[xp] = po[yi][xp];
    }
    __syncthreads();

    u16* gout = vlocB + ((size_t)b * DH_ + sub * 64) * N_;
    #pragma unroll
    for (int i = 0; i < 7; i++) {
        int g = i * 256 + tid;
        if (g < 1568)
            *(v8s*)&gout[g * 8] = *(const v8s*)&V[g * 8];
    }
}

// ---------------------------------------------------------------------------
// K3: FUSED attention, latency-lean version. Block = (qtile8, b), 1600 blocks,
// 29.4 KB LDS -> 5 blocks/CU. Phases:
//  A  scores via MFMA -> Sl[h][q8][228] fp16
//  B1 per-column (no sync): +abT1 bias, TH1, exp(A-5) in-place fp16
//  B2 row sums: 64 rows x 4 threads, vectorized u32 LDS reads -> invS
//  B3 per-column: scale + TH2 in-place (bf16)
//  C  copy-out to P image, 128B-contiguous chunks
// ---------------------------------------------------------------------------
__global__ __launch_bounds__(256) void k_attn(
    const u16* __restrict__ qI, const u16* __restrict__ kI,
    const float* __restrict__ th1w,
    const float* __restrict__ th2w, const float* __restrict__ th2b,
    const float* __restrict__ abT1, const int* __restrict__ bidx,
    u16* __restrict__ PbI)
{
    __shared__ u16 Sl[8 * 8 * 228];   // [h][q][m] = 29184 B
    __shared__ float red[64][4];
    __shared__ float invS[64];        // [h*8+q]
    const int tid = threadIdx.x;
    const int w = tid >> 6, lane = tid & 63;
    const int quad = lane >> 4, l16 = lane & 15;
    const int qt = blockIdx.x, b = blockIdx.y;   // qt 0..24
    const int n0 = qt * 8;

    // phase A: wave w -> heads 2w, 2w+1; keep q-rows quad<2
    #pragma unroll
    for (int hh = 0; hh < 2; hh++) {
        int h = w * 2 + hh;
        const u16* qb = qI + (size_t)(b * 8 + h) * 8192;
        const u16* kb = kI + (size_t)(b * 8 + h) * 8192;
        v8s a = *(const v8s*)&qb[(n0 + l16) * 32 + quad * 8];
        for (int mt = 0; mt < 13; mt++) {
            v8s bfr = *(const v8s*)&kb[(mt * 16 + l16) * 32 + quad * 8];
            v4f acc = {};
            acc = __builtin_amdgcn_mfma_f32_16x16x32_bf16(a, bfr, acc, 0, 0, 0);
            if (quad < 2) {
                #pragma unroll
                for (int r = 0; r < 4; r++) {
                    int q = quad * 4 + r;
                    Sl[(h * 8 + q) * 228 + mt * 16 + l16] = f2h(acc[r]);
                }
            }
        }
    }
    __syncthreads();

    // phase B1: thread owns column m; no syncs; exp(A-5) in place (fp16)
    const int m = tid;
    const bool mact = (m < N_);
    for (int q = 0; q < 8; q++) {
        int n = n0 + q;
        if (mact && n < N_) {
            int idx = bidx[n * N_ + m];
            v4f b0 = *(const v4f*)&abT1[idx * 8];
            v4f b1 = *(const v4f*)&abT1[idx * 8 + 4];
            float S[8];
            #pragma unroll
            for (int h = 0; h < 8; h++) S[h] = h2f(Sl[(h * 8 + q) * 228 + m]);
            float E[8];
            #pragma unroll
            for (int o = 0; o < 8; o++) {
                float a = ((o < 4) ? b0[o] : b1[o - 4]) - 5.f;
                #pragma unroll
                for (int h = 0; h < 8; h++) a += th1w[o * 8 + h] * S[h];
                E[o] = __expf(a);
            }
            #pragma unroll
            for (int o = 0; o < 8; o++)
                Sl[(o * 8 + q) * 228 + m] = f2h(E[o]);
        }
    }
    __syncthreads();

    // phase B2: 64 rows (o*8+q) x 4 threads; m chunks 48,48,48,52
    {
        int r = tid >> 2, quarter = tid & 3;
        int mstart = quarter * 48;
        int cnt = (quarter == 3) ? 26 : 24;
        const u16* rowp = &Sl[r * 228 + mstart];
        float s = 0.f;
        for (int i = 0; i < cnt; i++) {
            u32 u = *(const u32*)&rowp[i * 2];
            s += h2f((u16)(u & 0xffffu)) + h2f((u16)(u >> 16));
        }
        red[r][quarter] = s;
    }
    __syncthreads();
    if (tid < 64)
        invS[tid] = 1.f / (red[tid][0] + red[tid][1] + red[tid][2] + red[tid][3]);
    __syncthreads();

    // phase B3: thread owns column m; scale + TH2 in place (bf16)
    for (int q = 0; q < 8; q++) {
        bool valid = mact && (n0 + q < N_);
        float p[8];
        if (valid) {
            float sc[8];
            #pragma unroll
            for (int h = 0; h < 8; h++)
                sc[h] = h2f(Sl[(h * 8 + q) * 228 + m]) * invS[h * 8 + q];
            #pragma unroll
            for (int o = 0; o < 8; o++) {
                float v = th2b[o];
                #pragma unroll
                for (int h = 0; h < 8; h++) v += th2w[o * 8 + h] * sc[h];
                p[o] = v;
            }
        }
        if (m < 224) {
            #pragma unroll
            for (int o = 0; o < 8; o++)
                Sl[(o * 8 + q) * 228 + m] = valid ? f2bf(p[o]) : (u16)0;
        }
    }
    __syncthreads();

    // phase C: copy P -> global image; 2 chunks (128B) per wave-instr
    const int half = n0 >> 7;
    const int row0 = n0 & 127;
    {
        int lq = (lane & 31) >> 2, jj = lane & 3;
        for (int i = 0; i < 28; i++) {
            int ch = w * 56 + i * 2 + (lane >> 5);      // 0..223
            int o = ch / 28, rem = ch - o * 28;
            int ks = rem >> 2, kq = rem & 3;
            u32 val = *(const u32*)&Sl[(o * 8 + lq) * 228 + ks * 32 + kq * 8 + jj * 2];
            u16* dst = PbI + ((size_t)(b * 8 + o) * 2 + half) * 28672
                     + ks * 4096 + kq * 1024 + (row0 + lq) * 8 + jj * 2;
            *(u32*)dst = val;
        }
    }
}

// ---------------------------------------------------------------------------
// K5: attn @ V (K=224, 7 ksteps) + v_local(bf16) + relu -> aoI image
// ---------------------------------------------------------------------------
__global__ __launch_bounds__(256) void k_av(
    const u16* __restrict__ vI, const u16* __restrict__ PbI,
    const u16* __restrict__ vlocB, u16* __restrict__ aoI)
{
    __shared__ u16 sA[4096];
    __shared__ u16 sB[4096];
    const int tid = threadIdx.x;
    const int nt = blockIdx.x;
    const int o  = blockIdx.y;
    const int b  = blockIdx.z;
    v4f acc[4][4] = {};
    gemm_core_g(vI + (size_t)(b * 8 + o) * 28672,
                PbI + ((size_t)(b * 8 + o) * 2 + nt) * 28672, 7, sA, sB, acc, tid);

    const int lane = tid & 63, w = tid >> 6;
    const int wm = (w & 1) * 64, wn = (w >> 1) * 64;
    const int quad = lane >> 4, l16 = lane & 15;
    #pragma unroll
    for (int i = 0; i < 4; i++) {
        #pragma unroll
        for (int j = 0; j < 4; j++) {
            int lr = wm + i * 16 + quad * 4;        // e base
            int c0 = o * 128 + lr;                  // global k-index base
            int n  = nt * 128 + wn + j * 16 + l16;  // token (0..255)
            v4u u;
            #pragma unroll
            for (int r = 0; r < 4; r++) {
                u16 outv = 0;
                if (n < N_) {
                    float val = acc[i][j][r] + bf2f(vlocB[((size_t)b * DH_ + c0 + r) * N_ + n]);
                    outv = f2bf(fmaxf(val, 0.f));
                }
                u[r] = outv;
            }
            *(v4u*)&aoI[((size_t)(b * 2 + nt) * 32 + (c0 >> 5)) * 4096
                        + ((c0 >> 3) & 3) * 1024 + (n & 127) * 8 + (c0 & 7)] = u;
        }
    }
}

// ---------------------------------------------------------------------------
// K6: projection GEMM (K=1024, 32 ksteps) + BN -> out fp32
// ---------------------------------------------------------------------------
__global__ __launch_bounds__(256) void k_proj(
    const u16* __restrict__ WpI, const u16* __restrict__ aoI,
    const float* __restrict__ TB, float* __restrict__ out)
{
    __shared__ u16 sA[4096];
    __shared__ u16 sB[4096];
    const int tid = threadIdx.x;
    const int nt = blockIdx.x;
    const int mt = blockIdx.y;
    const int b  = blockIdx.z;
    v4f acc[4][4] = {};
    gemm_core_g(WpI + (size_t)mt * 131072,
                aoI + (size_t)(b * 2 + nt) * 131072, 32, sA, sB, acc, tid);

    const int lane = tid & 63, w = tid >> 6;
    const int wm = (w & 1) * 64, wn = (w >> 1) * 64;
    const int quad = lane >> 4, l16 = lane & 15;
    #pragma unroll
    for (int i = 0; i < 4; i++) {
        #pragma unroll
        for (int j = 0; j < 4; j++) {
            int p0 = mt * 128 + wm + i * 16 + quad * 4;
            int n  = nt * 128 + wn + j * 16 + l16;
            if (n < N_) {
                v4f s = *(const v4f*)&TB[3072 + p0];
                v4f t = *(const v4f*)&TB[3456 + p0];
                #pragma unroll
                for (int r = 0; r < 4; r++)
                    out[((size_t)b * DIM_ + p0 + r) * N_ + n] = acc[i][j][r] * s[r] + t[r];
            }
        }
    }
}

// ---------------------------------------------------------------------------
extern "C" void kernel_launch(void* const* d_in, const int* in_sizes, int n_in,
                              void* d_out, int out_size, void* d_ws, size_t ws_size,
                              hipStream_t stream)
{
    const float* x    = (const float*)d_in[0];
    const float* wq   = (const float*)d_in[1];
    const float* bq   = (const float*)d_in[2];
    const float* bnq  = (const float*)d_in[3];
    const float* wk   = (const float*)d_in[4];
    const float* bk   = (const float*)d_in[5];
    const float* bnk  = (const float*)d_in[6];
    const float* wv   = (const float*)d_in[7];
    const float* bv   = (const float*)d_in[8];
    const float* bnv  = (const float*)d_in[9];
    const float* wvl  = (const float*)d_in[10];
    const float* bvl  = (const float*)d_in[11];
    const float* bnvl = (const float*)d_in[12];
    const float* th1w = (const float*)d_in[13];
    const float* th1b = (const float*)d_in[14];
    const float* th2w = (const float*)d_in[15];
    const float* th2b = (const float*)d_in[16];
    const float* wp   = (const float*)d_in[17];
    const float* bp   = (const float*)d_in[18];
    const float* bnp  = (const float*)d_in[19];
    const float* ab   = (const float*)d_in[20];
    const int*   bidx = (const int*)d_in[21];
    float* out = (float*)d_out;

    u16* wsb  = (u16*)d_ws;
    u16* WbI  = wsb + WBI_OFF;
    u16* WpI  = wsb + WPI_OFF;
    u16* qI   = wsb + QI_OFF;
    u16* kI   = wsb + KI_OFF;
    u16* vI   = wsb + VI_OFF;
    u16* PbI  = wsb + PBI_OFF;
    u16* vlocB = wsb + VLOC_U16;
    u16* xI   = wsb + TAIL_OFF;   // aliased: xI -> aoI (disjoint lifetimes)
    u16* aoI  = wsb + TAIL_OFF;
    float* TB   = (float*)(wsb + TB_OFF);
    float* abT1 = (float*)(wsb + ABT_OFF);

    k_castW<<<dim3(3859), 256, 0, stream>>>(wq, wk, wv, wp, ab, th1w, th1b,
                                            bq, bnq, bk, bnk, bv, bnv, bp, bnp, bvl, bnvl,
                                            WbI, WpI, abT1, TB);
    k_castX<<<dim3(4, 6, B_), 256, 0, stream>>>(x, xI);
    k_qkv<<<dim3(2, 12, B_), 256, 0, stream>>>(WbI, xI, TB, qI, kI, vI);
    k_dwconv<<<dim3(16, B_), 256, 0, stream>>>(vI, wvl, TB, vlocB);
    k_attn<<<dim3(25, B_), 256, 0, stream>>>(qI, kI, th1w, th2w, th2b, abT1, bidx, PbI);
    k_av<<<dim3(2, HEADS_, B_), 256, 0, stream>>>(vI, PbI, vlocB, aoI);
    k_proj<<<dim3(2, 3, B_), 256, 0, stream>>>(WpI, aoI, TB, out);
}

// Round 9
// 324.346 us; speedup vs baseline: 1.2032x; 1.0135x over previous
//
#include <hip/hip_runtime.h>

#define B_     64
#define DIM_   384
#define RES_   14
#define N_     196
#define HEADS_ 8
#define KD_    32
#define D_     128
#define DH_    1024
#define QK_    256
#define CH_    1536
#define EPS_   1e-5f
#define SCALE_ 0.17677669529663687f   // 32^-0.5

typedef unsigned short u16;
typedef unsigned int u32;
typedef short v8s __attribute__((ext_vector_type(8)));
typedef float v4f __attribute__((ext_vector_type(4)));
typedef u16  v4u __attribute__((ext_vector_type(4)));

static __device__ __forceinline__ u16 f2bf(float f) {
    unsigned int u = __builtin_bit_cast(unsigned int, f);
    u = (u + 0x7fffu + ((u >> 16) & 1u)) >> 16;
    return (u16)u;
}
static __device__ __forceinline__ float bf2f(u16 u) {
    unsigned int x = ((unsigned int)u) << 16;
    return __builtin_bit_cast(float, x);
}
static __device__ __forceinline__ u16 f2h(float f) {
    _Float16 h = (_Float16)f;
    return __builtin_bit_cast(u16, h);
}
static __device__ __forceinline__ float h2f(u16 u) {
    return (float)__builtin_bit_cast(_Float16, u);
}

// workspace layout (u16 element offsets)
// GEMM operand images: [kstep][kquad(4)][row(128)][8] = 4096 elems (8KB)/kstep
#define WBI_OFF  0u          // Wb  image: 12 mtiles x 12 ksteps      (589824)
#define WPI_OFF  589824u     // wp  image: 3 mtiles x 32 ksteps       (393216)
#define QI_OFF   983040u     // qT  [B][8][256][32]                   (4194304)
#define KI_OFF   5177344u    // kT  [B][8][256][32]                   (4194304)
#define VI_OFF   9371648u    // v   image: [B][8] x 7 ksteps          (14680064)
#define PBI_OFF  24051712u   // P   image: [B][8][nt2] x 7 ksteps     (29360128)
#define VLOC_U16 53411840u   // vlocI in aoI image layout             (16777216)
#define TAIL_OFF 79101952u   // union: xI (6291456) / aoI (16777216)
#define TB_OFF   98770944u   // BN tables fp32[5888]
#define ABT_OFF  98782720u   // abT1 [196][8] fp32 (th1-folded bias)

// ---------------------------------------------------------------------------
// barrier-free direct-from-global 128x128 MFMA core. Operands pre-packed in
// fragment order; each wave streams its own fragments (L1/L2 dedupe the 2x
// overlap), 2-deep software pipeline, NO LDS, NO __syncthreads.
// ---------------------------------------------------------------------------
template<int KSTEPS>
static __device__ __forceinline__ void gemm_direct(
    const u16* __restrict__ Ag, const u16* __restrict__ Bg,
    v4f acc[4][4], int tid)
{
    const int lane = tid & 63, w = tid >> 6;
    const int wm = (w & 1) * 64, wn = (w >> 1) * 64;
    const int quad = lane >> 4, l16 = lane & 15;
    const u16* pa = Ag + quad * 1024 + (wm + l16) * 8;
    const u16* pb = Bg + quad * 1024 + (wn + l16) * 8;
    v8s a[2][4], b[2][4];
    #pragma unroll
    for (int i = 0; i < 4; i++) {
        a[0][i] = *(const v8s*)(pa + i * 128);
        b[0][i] = *(const v8s*)(pb + i * 128);
    }
    #pragma unroll
    for (int ks = 0; ks < KSTEPS; ks++) {
        const int cur = ks & 1, nxt = cur ^ 1;
        if (ks + 1 < KSTEPS) {
            const u16* qa = pa + (size_t)(ks + 1) * 4096;
            const u16* qb = pb + (size_t)(ks + 1) * 4096;
            #pragma unroll
            for (int i = 0; i < 4; i++) {
                a[nxt][i] = *(const v8s*)(qa + i * 128);
                b[nxt][i] = *(const v8s*)(qb + i * 128);
            }
        }
        #pragma unroll
        for (int i = 0; i < 4; i++)
            #pragma unroll
            for (int j = 0; j < 4; j++)
                acc[i][j] = __builtin_amdgcn_mfma_f32_16x16x32_bf16(a[cur][i], b[cur][j], acc[i][j], 0, 0, 0);
    }
}

// ---------------------------------------------------------------------------
// pack weights into tile images + abT1 (th1-folded bias) + BN tables
// ---------------------------------------------------------------------------
__global__ __launch_bounds__(256) void k_castW(
    const float* __restrict__ wq, const float* __restrict__ wk,
    const float* __restrict__ wv, const float* __restrict__ wp,
    const float* __restrict__ ab,
    const float* __restrict__ th1w, const float* __restrict__ th1b,
    const float* __restrict__ bq, const float* __restrict__ bnq,
    const float* __restrict__ bk, const float* __restrict__ bnk,
    const float* __restrict__ bv, const float* __restrict__ bnv,
    const float* __restrict__ bp, const float* __restrict__ bnp,
    const float* __restrict__ bvl, const float* __restrict__ bnvl,
    u16* __restrict__ WbI, u16* __restrict__ WpI,
    float* __restrict__ abT1, float* __restrict__ TB)
{
    int i = blockIdx.x * 256 + threadIdx.x;
    if (i < 589824) {           // qkv weight image
        int mt = i / 49152, rem = i % 49152;
        int ks = rem >> 12, r2 = rem & 4095;
        int q = r2 >> 10, row = (r2 >> 3) & 127, e = r2 & 7;
        int c = mt * 128 + row, k = ks * 32 + q * 8 + e;
        float v = (c < 256) ? wq[c * 384 + k]
                : (c < 512) ? wk[(c - 256) * 384 + k]
                            : wv[(size_t)(c - 512) * 384 + k];
        WbI[i] = f2bf(v);
    } else if (i < 983040) {    // proj weight image
        int j = i - 589824;
        int mt = j >> 17, rem = j & 131071;
        int ks = rem >> 12, r2 = rem & 4095;
        int q = r2 >> 10, row = (r2 >> 3) & 127, e = r2 & 7;
        int p = mt * 128 + row, k = ks * 32 + q * 8 + e;
        WpI[j] = f2bf(wp[(size_t)p * 1024 + k]);
    } else if (i < 984608) {    // abT1[idx][o] = th1b[o] + sum_h th1w[o][h]*ab[h][idx]
        int j = i - 983040;
        int idx = j >> 3, o = j & 7;
        float a = th1b[o];
        #pragma unroll
        for (int h = 0; h < 8; h++) a += th1w[o * 8 + h] * ab[h * N_ + idx];
        abT1[j] = a;
    } else if (i < 987552) {    // BN tables
        int j = i - 984608;
        if (j < 256) {
            int c = j;
            float s = bnq[c] * rsqrtf(bnq[768 + c] + EPS_);
            float t = (bq[c] - bnq[512 + c]) * s + bnq[256 + c];
            TB[c] = s * SCALE_; TB[256 + c] = t * SCALE_;
        } else if (j < 512) {
            int c = j - 256;
            float s = bnk[c] * rsqrtf(bnk[768 + c] + EPS_);
            float t = (bk[c] - bnk[512 + c]) * s + bnk[256 + c];
            TB[512 + c] = s; TB[768 + c] = t;
        } else if (j < 1536) {
            int c = j - 512;
            float s = bnv[c] * rsqrtf(bnv[3072 + c] + EPS_);
            float t = (bv[c] - bnv[2048 + c]) * s + bnv[1024 + c];
            TB[1024 + c] = s; TB[2048 + c] = t;
        } else if (j < 1920) {
            int c = j - 1536;
            float s = bnp[c] * rsqrtf(bnp[1152 + c] + EPS_);
            float t = (bp[c] - bnp[768 + c]) * s + bnp[384 + c];
            TB[3072 + c] = s; TB[3456 + c] = t;
        } else {
            int c = j - 1920;
            float s = bnvl[c] * rsqrtf(bnvl[3072 + c] + EPS_);
            float t = (bvl[c] - bnvl[2048 + c]) * s + bnvl[1024 + c];
            TB[3840 + c] = s; TB[4864 + c] = t;
        }
    }
}

// ---------------------------------------------------------------------------
// x [B,384,196] fp32 -> xI image [B][nt2][12 ksteps][4096] bf16 (n>=196 zero)
// ---------------------------------------------------------------------------
__global__ __launch_bounds__(256) void k_castX(
    const float* __restrict__ x, u16* __restrict__ xI)
{
    __shared__ float T[64][65];
    const int tid = threadIdx.x;
    const int n0 = blockIdx.x * 64;
    const int k0 = blockIdx.y * 64;
    const int b  = blockIdx.z;
    const int c = tid & 63, r4 = tid >> 6;
    #pragma unroll
    for (int i = 0; i < 16; i++) {
        int kr = i * 4 + r4;
        int gn = n0 + c;
        T[kr][c] = (gn < N_) ? x[((size_t)b * DIM_ + k0 + kr) * N_ + gn] : 0.f;
    }
    __syncthreads();
    #pragma unroll
    for (int it = 0; it < 16; it++) {
        int j = it * 256 + tid;
        int kk = j & 63, nn = j >> 6;
        int k = k0 + kk, n = n0 + nn;
        xI[(size_t)b * 98304 + (n >> 7) * 49152 + (k >> 5) * 4096
           + ((k >> 3) & 3) * 1024 + (n & 127) * 8 + (k & 7)] = f2bf(T[kk][nn]);
    }
}

// ---------------------------------------------------------------------------
// K1: QKV GEMM (direct core). qI/kI [b][h][256][32] bf16 (q pre-scaled),
// vI image per (b,o), 7 ksteps (n>=196 zero).
// ---------------------------------------------------------------------------
__global__ __launch_bounds__(256) void k_qkv(
    const u16* __restrict__ WbI, const u16* __restrict__ xI,
    const float* __restrict__ TB,
    u16* __restrict__ qI, u16* __restrict__ kI, u16* __restrict__ vI)
{
    const int tid = threadIdx.x;
    const int nt = blockIdx.x;
    const int mt = blockIdx.y;
    const int b  = blockIdx.z;
    v4f acc[4][4] = {};
    gemm_direct<12>(WbI + (size_t)mt * 49152,
                    xI + ((size_t)b * 2 + nt) * 49152, acc, tid);

    const int lane = tid & 63, w = tid >> 6;
    const int wm = (w & 1) * 64, wn = (w >> 1) * 64;
    const int quad = lane >> 4, l16 = lane & 15;
    #pragma unroll
    for (int i = 0; i < 4; i++) {
        #pragma unroll
        for (int j = 0; j < 4; j++) {
            int gc = mt * 128 + wm + i * 16 + quad * 4;  // global channel base
            int n  = nt * 128 + wn + j * 16 + l16;       // token (0..255)
            v4f v = acc[i][j];
            if (gc < 256) {            // q
                v4f s = *(const v4f*)&TB[gc];
                v4f t = *(const v4f*)&TB[256 + gc];
                v4u u;
                #pragma unroll
                for (int r = 0; r < 4; r++) u[r] = f2bf(v[r] * s[r] + t[r]);
                *(v4u*)&qI[((size_t)(b * 8 + (gc >> 5)) * 256 + n) * 32 + (gc & 31)] = u;
            } else if (gc < 512) {     // k
                int c = gc - 256;
                v4f s = *(const v4f*)&TB[512 + c];
                v4f t = *(const v4f*)&TB[768 + c];
                v4u u;
                #pragma unroll
                for (int r = 0; r < 4; r++) u[r] = f2bf(v[r] * s[r] + t[r]);
                *(v4u*)&kI[((size_t)(b * 8 + (c >> 5)) * 256 + n) * 32 + (c & 31)] = u;
            } else {                   // v -> image (row = e, col = n as k-dim)
                int c = gc - 512;      // 0..1023
                if (n < 224) {
                    int o = c >> 7, e = c & 127;
                    u16* base = vI + ((size_t)(b * 8 + o) * 7 + (n >> 5)) * 4096
                                + ((n >> 3) & 3) * 1024 + (n & 7);
                    #pragma unroll
                    for (int r = 0; r < 4; r++) {
                        u16 outv = 0;
                        if (n < N_) outv = f2bf(v[r] * TB[1024 + c + r] + TB[2048 + c + r]);
                        base[(e + r) * 8] = outv;
                    }
                }
            }
        }
    }
}

// ---------------------------------------------------------------------------
// K2: depthwise 3x3 conv. Block = 64 channels of one (b,o).
// Phase 3 now writes vlocI in the aoI IMAGE layout so k_av reads vectorized.
// ---------------------------------------------------------------------------
__global__ __launch_bounds__(256) void k_dwconv(
    const u16* __restrict__ vI, const float* __restrict__ wvl,
    const float* __restrict__ TB, u16* __restrict__ vlocI)
{
    __shared__ u16 V[64 * 230];             // 29440 B
    const int tid = threadIdx.x;
    const int sub = blockIdx.x;             // 0..15: o = sub>>1, half = sub&1
    const int b   = blockIdx.y;
    const int o   = sub >> 1;
    const int e0  = (sub & 1) * 64;
    const u16* img = vI + (size_t)(b * 8 + o) * 28672;

    {
        const int quad = tid >> 6, l = tid & 63;
        #pragma unroll
        for (int i = 0; i < 7; i++) {
            v8s u = *(const v8s*)&img[i * 4096 + quad * 1024 + (e0 + l) * 8];
            const u32* ui = (const u32*)&u;
            int m0 = i * 32 + quad * 8;
            u32* dst = (u32*)&V[l * 230 + m0];
            #pragma unroll
            for (int c = 0; c < 4; c++) dst[c] = ui[c];
        }
    }
    __syncthreads();

    const int e = tid & 63, j = tid >> 6;
    const int cg = sub * 64 + e;
    const int y0 = j * 4;
    const int ny = (j == 3) ? 2 : 4;
    float wgt[9];
    #pragma unroll
    for (int k = 0; k < 9; k++) wgt[k] = wvl[cg * 9 + k];
    const float sc = TB[3840 + cg], sh = TB[4864 + cg];
    u32 po[4][7];

    for (int yi = 0; yi < ny; yi++) {
        int y = y0 + yi;
        float a[3][16];
        #pragma unroll
        for (int dy = 0; dy < 3; dy++) {
            int yy = y + dy - 1;
            a[dy][0] = 0.f; a[dy][15] = 0.f;
            if (yy < 0 || yy > 13) {
                #pragma unroll
                for (int x = 1; x < 15; x++) a[dy][x] = 0.f;
            } else {
                const u16* rp = &V[e * 230 + yy * 14];
                #pragma unroll
                for (int c4 = 0; c4 < 7; c4++) {
                    u32 u = *(const u32*)&rp[c4 * 2];
                    a[dy][1 + 2 * c4] = bf2f((u16)(u & 0xffffu));
                    a[dy][2 + 2 * c4] = bf2f((u16)(u >> 16));
                }
            }
        }
        #pragma unroll
        for (int xp = 0; xp < 7; xp++) {
            u32 pk = 0;
            #pragma unroll
            for (int half = 0; half < 2; half++) {
                int x = 2 * xp + half;
                float s = 0.f;
                #pragma unroll
                for (int dy = 0; dy < 3; dy++)
                    #pragma unroll
                    for (int kx = 0; kx < 3; kx++)
                        s += wgt[dy * 3 + kx] * a[dy][x + kx];
                u16 bv = f2bf(s * sc + sh);
                pk |= ((u32)bv) << (16 * half);
            }
            po[yi][xp] = pk;
        }
    }
    __syncthreads();

    // stash flat O[e][n]
    for (int yi = 0; yi < ny; yi++) {
        u32* dst = (u32*)&V[e * 196 + (y0 + yi) * 14];
        #pragma unroll
        for (int xp = 0; xp < 7; xp++) dst[xp] = po[yi][xp];
    }
    __syncthreads();

    // write out in aoI image layout: 16B per (channel-group-of-8, token)
    for (int it = 0; it < 7; it++) {
        int idx = it * 256 + tid;
        if (idx < 1568) {
            int g = idx / 196, n = idx - g * 196;
            v4u lo, hi;
            #pragma unroll
            for (int r = 0; r < 4; r++) lo[r] = V[(g * 8 + r) * 196 + n];
            #pragma unroll
            for (int r = 0; r < 4; r++) hi[r] = V[(g * 8 + 4 + r) * 196 + n];
            u16* dst = vlocI + ((size_t)(b * 2 + (n >> 7)) * 32 + sub * 2 + (g >> 2)) * 4096
                     + (g & 3) * 1024 + (n & 127) * 8;
            *(v4u*)dst = lo;
            *(v4u*)(dst + 4) = hi;
        }
    }
}

// ---------------------------------------------------------------------------
// K3: FUSED attention (unchanged from R8). Block = (qtile8, b).
// ---------------------------------------------------------------------------
__global__ __launch_bounds__(256) void k_attn(
    const u16* __restrict__ qI, const u16* __restrict__ kI,
    const float* __restrict__ th1w,
    const float* __restrict__ th2w, const float* __restrict__ th2b,
    const float* __restrict__ abT1, const int* __restrict__ bidx,
    u16* __restrict__ PbI)
{
    __shared__ u16 Sl[8 * 8 * 228];   // [h][q][m] = 29184 B
    __shared__ float red[64][4];
    __shared__ float invS[64];        // [h*8+q]
    const int tid = threadIdx.x;
    const int w = tid >> 6, lane = tid & 63;
    const int quad = lane >> 4, l16 = lane & 15;
    const int qt = blockIdx.x, b = blockIdx.y;   // qt 0..24
    const int n0 = qt * 8;

    #pragma unroll
    for (int hh = 0; hh < 2; hh++) {
        int h = w * 2 + hh;
        const u16* qb = qI + (size_t)(b * 8 + h) * 8192;
        const u16* kb = kI + (size_t)(b * 8 + h) * 8192;
        v8s a = *(const v8s*)&qb[(n0 + l16) * 32 + quad * 8];
        for (int mt = 0; mt < 13; mt++) {
            v8s bfr = *(const v8s*)&kb[(mt * 16 + l16) * 32 + quad * 8];
            v4f acc = {};
            acc = __builtin_amdgcn_mfma_f32_16x16x32_bf16(a, bfr, acc, 0, 0, 0);
            if (quad < 2) {
                #pragma unroll
                for (int r = 0; r < 4; r++) {
                    int q = quad * 4 + r;
                    Sl[(h * 8 + q) * 228 + mt * 16 + l16] = f2h(acc[r]);
                }
            }
        }
    }
    __syncthreads();

    const int m = tid;
    const bool mact = (m < N_);
    for (int q = 0; q < 8; q++) {
        int n = n0 + q;
        if (mact && n < N_) {
            int idx = bidx[n * N_ + m];
            v4f b0 = *(const v4f*)&abT1[idx * 8];
            v4f b1 = *(const v4f*)&abT1[idx * 8 + 4];
            float S[8];
            #pragma unroll
            for (int h = 0; h < 8; h++) S[h] = h2f(Sl[(h * 8 + q) * 228 + m]);
            float E[8];
            #pragma unroll
            for (int o = 0; o < 8; o++) {
                float a = ((o < 4) ? b0[o] : b1[o - 4]) - 5.f;
                #pragma unroll
                for (int h = 0; h < 8; h++) a += th1w[o * 8 + h] * S[h];
                E[o] = __expf(a);
            }
            #pragma unroll
            for (int o = 0; o < 8; o++)
                Sl[(o * 8 + q) * 228 + m] = f2h(E[o]);
        }
    }
    __syncthreads();

    {
        int r = tid >> 2, quarter = tid & 3;
        int mstart = quarter * 48;
        int cnt = (quarter == 3) ? 26 : 24;
        const u16* rowp = &Sl[r * 228 + mstart];
        float s = 0.f;
        for (int i = 0; i < cnt; i++) {
            u32 u = *(const u32*)&rowp[i * 2];
            s += h2f((u16)(u & 0xffffu)) + h2f((u16)(u >> 16));
        }
        red[r][quarter] = s;
    }
    __syncthreads();
    if (tid < 64)
        invS[tid] = 1.f / (red[tid][0] + red[tid][1] + red[tid][2] + red[tid][3]);
    __syncthreads();

    for (int q = 0; q < 8; q++) {
        bool valid = mact && (n0 + q < N_);
        float p[8];
        if (valid) {
            float sc[8];
            #pragma unroll
            for (int h = 0; h < 8; h++)
                sc[h] = h2f(Sl[(h * 8 + q) * 228 + m]) * invS[h * 8 + q];
            #pragma unroll
            for (int o = 0; o < 8; o++) {
                float v = th2b[o];
                #pragma unroll
                for (int h = 0; h < 8; h++) v += th2w[o * 8 + h] * sc[h];
                p[o] = v;
            }
        }
        if (m < 224) {
            #pragma unroll
            for (int o = 0; o < 8; o++)
                Sl[(o * 8 + q) * 228 + m] = valid ? f2bf(p[o]) : (u16)0;
        }
    }
    __syncthreads();

    const int half = n0 >> 7;
    const int row0 = n0 & 127;
    {
        int lq = (lane & 31) >> 2, jj = lane & 3;
        for (int i = 0; i < 28; i++) {
            int ch = w * 56 + i * 2 + (lane >> 5);      // 0..223
            int o = ch / 28, rem = ch - o * 28;
            int ks = rem >> 2, kq = rem & 3;
            u32 val = *(const u32*)&Sl[(o * 8 + lq) * 228 + ks * 32 + kq * 8 + jj * 2];
            u16* dst = PbI + ((size_t)(b * 8 + o) * 2 + half) * 28672
                     + ks * 4096 + kq * 1024 + (row0 + lq) * 8 + jj * 2;
            *(u32*)dst = val;
        }
    }
}

// ---------------------------------------------------------------------------
// K5: attn @ V (direct core, K=224) + v_local(image) + relu -> aoI image
// ---------------------------------------------------------------------------
__global__ __launch_bounds__(256) void k_av(
    const u16* __restrict__ vI, const u16* __restrict__ PbI,
    const u16* __restrict__ vlocI, u16* __restrict__ aoI)
{
    const int tid = threadIdx.x;
    const int nt = blockIdx.x;
    const int o  = blockIdx.y;
    const int b  = blockIdx.z;
    v4f acc[4][4] = {};
    gemm_direct<7>(vI + (size_t)(b * 8 + o) * 28672,
                   PbI + ((size_t)(b * 8 + o) * 2 + nt) * 28672, acc, tid);

    const int lane = tid & 63, w = tid >> 6;
    const int wm = (w & 1) * 64, wn = (w >> 1) * 64;
    const int quad = lane >> 4, l16 = lane & 15;
    #pragma unroll
    for (int i = 0; i < 4; i++) {
        #pragma unroll
        for (int j = 0; j < 4; j++) {
            int lr = wm + i * 16 + quad * 4;        // e base
            int c0 = o * 128 + lr;                  // global channel base
            int n  = nt * 128 + wn + j * 16 + l16;  // token (0..255)
            size_t ioff = ((size_t)(b * 2 + nt) * 32 + (c0 >> 5)) * 4096
                        + ((c0 >> 3) & 3) * 1024 + (n & 127) * 8 + (c0 & 7);
            v4u lv = *(const v4u*)&vlocI[ioff];
            v4u u;
            #pragma unroll
            for (int r = 0; r < 4; r++) {
                u16 outv = 0;
                if (n < N_) {
                    float val = acc[i][j][r] + bf2f(lv[r]);
                    outv = f2bf(fmaxf(val, 0.f));
                }
                u[r] = outv;
            }
            *(v4u*)&aoI[ioff] = u;
        }
    }
}

// ---------------------------------------------------------------------------
// K6: projection GEMM (direct core, K=1024) + BN -> out fp32
// ---------------------------------------------------------------------------
__global__ __launch_bounds__(256) void k_proj(
    const u16* __restrict__ WpI, const u16* __restrict__ aoI,
    const float* __restrict__ TB, float* __restrict__ out)
{
    const int tid = threadIdx.x;
    const int nt = blockIdx.x;
    const int mt = blockIdx.y;
    const int b  = blockIdx.z;
    v4f acc[4][4] = {};
    gemm_direct<32>(WpI + (size_t)mt * 131072,
                    aoI + ((size_t)b * 2 + nt) * 131072, acc, tid);

    const int lane = tid & 63, w = tid >> 6;
    const int wm = (w & 1) * 64, wn = (w >> 1) * 64;
    const int quad = lane >> 4, l16 = lane & 15;
    #pragma unroll
    for (int i = 0; i < 4; i++) {
        #pragma unroll
        for (int j = 0; j < 4; j++) {
            int p0 = mt * 128 + wm + i * 16 + quad * 4;
            int n  = nt * 128 + wn + j * 16 + l16;
            if (n < N_) {
                v4f s = *(const v4f*)&TB[3072 + p0];
                v4f t = *(const v4f*)&TB[3456 + p0];
                #pragma unroll
                for (int r = 0; r < 4; r++)
                    out[((size_t)b * DIM_ + p0 + r) * N_ + n] = acc[i][j][r] * s[r] + t[r];
            }
        }
    }
}

// ---------------------------------------------------------------------------
extern "C" void kernel_launch(void* const* d_in, const int* in_sizes, int n_in,
                              void* d_out, int out_size, void* d_ws, size_t ws_size,
                              hipStream_t stream)
{
    const float* x    = (const float*)d_in[0];
    const float* wq   = (const float*)d_in[1];
    const float* bq   = (const float*)d_in[2];
    const float* bnq  = (const float*)d_in[3];
    const float* wk   = (const float*)d_in[4];
    const float* bk   = (const float*)d_in[5];
    const float* bnk  = (const float*)d_in[6];
    const float* wv   = (const float*)d_in[7];
    const float* bv   = (const float*)d_in[8];
    const float* bnv  = (const float*)d_in[9];
    const float* wvl  = (const float*)d_in[10];
    const float* bvl  = (const float*)d_in[11];
    const float* bnvl = (const float*)d_in[12];
    const float* th1w = (const float*)d_in[13];
    const float* th1b = (const float*)d_in[14];
    const float* th2w = (const float*)d_in[15];
    const float* th2b = (const float*)d_in[16];
    const float* wp   = (const float*)d_in[17];
    const float* bp   = (const float*)d_in[18];
    const float* bnp  = (const float*)d_in[19];
    const float* ab   = (const float*)d_in[20];
    const int*   bidx = (const int*)d_in[21];
    float* out = (float*)d_out;

    u16* wsb  = (u16*)d_ws;
    u16* WbI  = wsb + WBI_OFF;
    u16* WpI  = wsb + WPI_OFF;
    u16* qI   = wsb + QI_OFF;
    u16* kI   = wsb + KI_OFF;
    u16* vI   = wsb + VI_OFF;
    u16* PbI  = wsb + PBI_OFF;
    u16* vlocI = wsb + VLOC_U16;
    u16* xI   = wsb + TAIL_OFF;   // aliased: xI -> aoI (disjoint lifetimes)
    u16* aoI  = wsb + TAIL_OFF;
    float* TB   = (float*)(wsb + TB_OFF);
    float* abT1 = (float*)(wsb + ABT_OFF);

    k_castW<<<dim3(3859), 256, 0, stream>>>(wq, wk, wv, wp, ab, th1w, th1b,
                                            bq, bnq, bk, bnk, bv, bnv, bp, bnp, bvl, bnvl,
                                            WbI, WpI, abT1, TB);
    k_castX<<<dim3(4, 6, B_), 256, 0, stream>>>(x, xI);
    k_qkv<<<dim3(2, 12, B_), 256, 0, stream>>>(WbI, xI, TB, qI, kI, vI);
    k_dwconv<<<dim3(16, B_), 256, 0, stream>>>(vI, wvl, TB, vlocI);
    k_attn<<<dim3(25, B_), 256, 0, stream>>>(qI, kI, th1w, th2w, th2b, abT1, bidx, PbI);
    k_av<<<dim3(2, HEADS_, B_), 256, 0, stream>>>(vI, PbI, vlocI, aoI);
    k_proj<<<dim3(2, 3, B_), 256, 0, stream>>>(WpI, aoI, TB, out);
}

// Round 10
// 292.912 us; speedup vs baseline: 1.3323x; 1.1073x over previous
//
#include <hip/hip_runtime.h>

#define B_     64
#define DIM_   384
#define RES_   14
#define N_     196
#define HEADS_ 8
#define KD_    32
#define D_     128
#define DH_    1024
#define QK_    256
#define CH_    1536
#define EPS_   1e-5f
#define SCALE_ 0.17677669529663687f   // 32^-0.5

typedef unsigned short u16;
typedef unsigned int u32;
typedef short v8s __attribute__((ext_vector_type(8)));
typedef float v4f __attribute__((ext_vector_type(4)));
typedef u16  v4u __attribute__((ext_vector_type(4)));

static __device__ __forceinline__ u16 f2bf(float f) {
    unsigned int u = __builtin_bit_cast(unsigned int, f);
    u = (u + 0x7fffu + ((u >> 16) & 1u)) >> 16;
    return (u16)u;
}
static __device__ __forceinline__ float bf2f(u16 u) {
    unsigned int x = ((unsigned int)u) << 16;
    return __builtin_bit_cast(float, x);
}
static __device__ __forceinline__ u16 f2h(float f) {
    _Float16 h = (_Float16)f;
    return __builtin_bit_cast(u16, h);
}
static __device__ __forceinline__ float h2f(u16 u) {
    return (float)__builtin_bit_cast(_Float16, u);
}

// workspace layout (u16 element offsets)
// GEMM operand images: [kstep][kquad(4)][row(128)][8] = 4096 elems (8KB)/kstep
#define WBI_OFF  0u          // Wb  image: 12 mtiles x 12 ksteps      (589824)
#define WPI_OFF  589824u     // wp  image: 3 mtiles x 32 ksteps       (393216)
#define QI_OFF   983040u     // qT  [B][8][256][32]                   (4194304)
#define KI_OFF   5177344u    // kT  [B][8][256][32]                   (4194304)
#define VI_OFF   9371648u    // v   image: [B][8] x 7 ksteps          (14680064)
#define PBI_OFF  24051712u   // P   image: [B][8][nt2] x 7 ksteps     (29360128)
#define VLOC_U16 53411840u   // vlocI in aoI image layout             (16777216)
#define TAIL_OFF 79101952u   // union: xI (6291456) / aoI (16777216)
#define TB_OFF   98770944u   // BN tables fp32[5888]
#define ABT_OFF  98782720u   // abT1 [196][8] fp32 (th1-folded bias)
#define BIASE_OFF 98785920u  // biasE [196][8][196] fp32 (614656 u16)

// ---------------------------------------------------------------------------
// barrier-free direct-from-global 128x128 MFMA core. Operands pre-packed in
// fragment order; 2-deep software pipeline, NO LDS, NO __syncthreads.
// ---------------------------------------------------------------------------
template<int KSTEPS>
static __device__ __forceinline__ void gemm_direct(
    const u16* __restrict__ Ag, const u16* __restrict__ Bg,
    v4f acc[4][4], int tid)
{
    const int lane = tid & 63, w = tid >> 6;
    const int wm = (w & 1) * 64, wn = (w >> 1) * 64;
    const int quad = lane >> 4, l16 = lane & 15;
    const u16* pa = Ag + quad * 1024 + (wm + l16) * 8;
    const u16* pb = Bg + quad * 1024 + (wn + l16) * 8;
    v8s a[2][4], b[2][4];
    #pragma unroll
    for (int i = 0; i < 4; i++) {
        a[0][i] = *(const v8s*)(pa + i * 128);
        b[0][i] = *(const v8s*)(pb + i * 128);
    }
    #pragma unroll
    for (int ks = 0; ks < KSTEPS; ks++) {
        const int cur = ks & 1, nxt = cur ^ 1;
        if (ks + 1 < KSTEPS) {
            const u16* qa = pa + (size_t)(ks + 1) * 4096;
            const u16* qb = pb + (size_t)(ks + 1) * 4096;
            #pragma unroll
            for (int i = 0; i < 4; i++) {
                a[nxt][i] = *(const v8s*)(qa + i * 128);
                b[nxt][i] = *(const v8s*)(qb + i * 128);
            }
        }
        #pragma unroll
        for (int i = 0; i < 4; i++)
            #pragma unroll
            for (int j = 0; j < 4; j++)
                acc[i][j] = __builtin_amdgcn_mfma_f32_16x16x32_bf16(a[cur][i], b[cur][j], acc[i][j], 0, 0, 0);
    }
}

// ---------------------------------------------------------------------------
// pack weights into tile images + abT1 (th1-folded bias) + BN tables
// ---------------------------------------------------------------------------
__global__ __launch_bounds__(256) void k_castW(
    const float* __restrict__ wq, const float* __restrict__ wk,
    const float* __restrict__ wv, const float* __restrict__ wp,
    const float* __restrict__ ab,
    const float* __restrict__ th1w, const float* __restrict__ th1b,
    const float* __restrict__ bq, const float* __restrict__ bnq,
    const float* __restrict__ bk, const float* __restrict__ bnk,
    const float* __restrict__ bv, const float* __restrict__ bnv,
    const float* __restrict__ bp, const float* __restrict__ bnp,
    const float* __restrict__ bvl, const float* __restrict__ bnvl,
    u16* __restrict__ WbI, u16* __restrict__ WpI,
    float* __restrict__ abT1, float* __restrict__ TB)
{
    int i = blockIdx.x * 256 + threadIdx.x;
    if (i < 589824) {           // qkv weight image
        int mt = i / 49152, rem = i % 49152;
        int ks = rem >> 12, r2 = rem & 4095;
        int q = r2 >> 10, row = (r2 >> 3) & 127, e = r2 & 7;
        int c = mt * 128 + row, k = ks * 32 + q * 8 + e;
        float v = (c < 256) ? wq[c * 384 + k]
                : (c < 512) ? wk[(c - 256) * 384 + k]
                            : wv[(size_t)(c - 512) * 384 + k];
        WbI[i] = f2bf(v);
    } else if (i < 983040) {    // proj weight image
        int j = i - 589824;
        int mt = j >> 17, rem = j & 131071;
        int ks = rem >> 12, r2 = rem & 4095;
        int q = r2 >> 10, row = (r2 >> 3) & 127, e = r2 & 7;
        int p = mt * 128 + row, k = ks * 32 + q * 8 + e;
        WpI[j] = f2bf(wp[(size_t)p * 1024 + k]);
    } else if (i < 984608) {    // abT1[idx][o] = th1b[o] + sum_h th1w[o][h]*ab[h][idx]
        int j = i - 983040;
        int idx = j >> 3, o = j & 7;
        float a = th1b[o];
        #pragma unroll
        for (int h = 0; h < 8; h++) a += th1w[o * 8 + h] * ab[h * N_ + idx];
        abT1[j] = a;
    } else if (i < 987552) {    // BN tables
        int j = i - 984608;
        if (j < 256) {
            int c = j;
            float s = bnq[c] * rsqrtf(bnq[768 + c] + EPS_);
            float t = (bq[c] - bnq[512 + c]) * s + bnq[256 + c];
            TB[c] = s * SCALE_; TB[256 + c] = t * SCALE_;
        } else if (j < 512) {
            int c = j - 256;
            float s = bnk[c] * rsqrtf(bnk[768 + c] + EPS_);
            float t = (bk[c] - bnk[512 + c]) * s + bnk[256 + c];
            TB[512 + c] = s; TB[768 + c] = t;
        } else if (j < 1536) {
            int c = j - 512;
            float s = bnv[c] * rsqrtf(bnv[3072 + c] + EPS_);
            float t = (bv[c] - bnv[2048 + c]) * s + bnv[1024 + c];
            TB[1024 + c] = s; TB[2048 + c] = t;
        } else if (j < 1920) {
            int c = j - 1536;
            float s = bnp[c] * rsqrtf(bnp[1152 + c] + EPS_);
            float t = (bp[c] - bnp[768 + c]) * s + bnp[384 + c];
            TB[3072 + c] = s; TB[3456 + c] = t;
        } else {
            int c = j - 1920;
            float s = bnvl[c] * rsqrtf(bnvl[3072 + c] + EPS_);
            float t = (bvl[c] - bnvl[2048 + c]) * s + bnvl[1024 + c];
            TB[3840 + c] = s; TB[4864 + c] = t;
        }
    }
}

// ---------------------------------------------------------------------------
// expand bias: biasE[n][o][m] = abT1[bidx[n][m]][o] - 5  (batch-independent)
// ---------------------------------------------------------------------------
__global__ __launch_bounds__(256) void k_bias(
    const float* __restrict__ abT1, const int* __restrict__ bidx,
    float* __restrict__ biasE)
{
    int i = blockIdx.x * 256 + threadIdx.x;
    if (i >= N_ * 8 * N_) return;
    int m = i % N_;
    int t = i / N_;
    int o = t & 7;
    int n = t >> 3;
    biasE[i] = abT1[bidx[n * N_ + m] * 8 + o] - 5.f;
}

// ---------------------------------------------------------------------------
// x [B,384,196] fp32 -> xI image [B][nt2][12 ksteps][4096] bf16 (n>=196 zero)
// ---------------------------------------------------------------------------
__global__ __launch_bounds__(256) void k_castX(
    const float* __restrict__ x, u16* __restrict__ xI)
{
    __shared__ float T[64][65];
    const int tid = threadIdx.x;
    const int n0 = blockIdx.x * 64;
    const int k0 = blockIdx.y * 64;
    const int b  = blockIdx.z;
    const int c = tid & 63, r4 = tid >> 6;
    #pragma unroll
    for (int i = 0; i < 16; i++) {
        int kr = i * 4 + r4;
        int gn = n0 + c;
        T[kr][c] = (gn < N_) ? x[((size_t)b * DIM_ + k0 + kr) * N_ + gn] : 0.f;
    }
    __syncthreads();
    #pragma unroll
    for (int it = 0; it < 16; it++) {
        int j = it * 256 + tid;
        int kk = j & 63, nn = j >> 6;
        int k = k0 + kk, n = n0 + nn;
        xI[(size_t)b * 98304 + (n >> 7) * 49152 + (k >> 5) * 4096
           + ((k >> 3) & 3) * 1024 + (n & 127) * 8 + (k & 7)] = f2bf(T[kk][nn]);
    }
}

// ---------------------------------------------------------------------------
// K1: QKV GEMM (direct core). qI/kI [b][h][256][32] bf16 (q pre-scaled),
// vI image per (b,o), 7 ksteps (n>=196 zero).
// ---------------------------------------------------------------------------
__global__ __launch_bounds__(256) void k_qkv(
    const u16* __restrict__ WbI, const u16* __restrict__ xI,
    const float* __restrict__ TB,
    u16* __restrict__ qI, u16* __restrict__ kI, u16* __restrict__ vI)
{
    const int tid = threadIdx.x;
    const int nt = blockIdx.x;
    const int mt = blockIdx.y;
    const int b  = blockIdx.z;
    v4f acc[4][4] = {};
    gemm_direct<12>(WbI + (size_t)mt * 49152,
                    xI + ((size_t)b * 2 + nt) * 49152, acc, tid);

    const int lane = tid & 63, w = tid >> 6;
    const int wm = (w & 1) * 64, wn = (w >> 1) * 64;
    const int quad = lane >> 4, l16 = lane & 15;
    #pragma unroll
    for (int i = 0; i < 4; i++) {
        #pragma unroll
        for (int j = 0; j < 4; j++) {
            int gc = mt * 128 + wm + i * 16 + quad * 4;  // global channel base
            int n  = nt * 128 + wn + j * 16 + l16;       // token (0..255)
            v4f v = acc[i][j];
            if (gc < 256) {            // q
                v4f s = *(const v4f*)&TB[gc];
                v4f t = *(const v4f*)&TB[256 + gc];
                v4u u;
                #pragma unroll
                for (int r = 0; r < 4; r++) u[r] = f2bf(v[r] * s[r] + t[r]);
                *(v4u*)&qI[((size_t)(b * 8 + (gc >> 5)) * 256 + n) * 32 + (gc & 31)] = u;
            } else if (gc < 512) {     // k
                int c = gc - 256;
                v4f s = *(const v4f*)&TB[512 + c];
                v4f t = *(const v4f*)&TB[768 + c];
                v4u u;
                #pragma unroll
                for (int r = 0; r < 4; r++) u[r] = f2bf(v[r] * s[r] + t[r]);
                *(v4u*)&kI[((size_t)(b * 8 + (c >> 5)) * 256 + n) * 32 + (c & 31)] = u;
            } else {                   // v -> image (row = e, col = n as k-dim)
                int c = gc - 512;      // 0..1023
                if (n < 224) {
                    int o = c >> 7, e = c & 127;
                    u16* base = vI + ((size_t)(b * 8 + o) * 7 + (n >> 5)) * 4096
                                + ((n >> 3) & 3) * 1024 + (n & 7);
                    #pragma unroll
                    for (int r = 0; r < 4; r++) {
                        u16 outv = 0;
                        if (n < N_) outv = f2bf(v[r] * TB[1024 + c + r] + TB[2048 + c + r]);
                        base[(e + r) * 8] = outv;
                    }
                }
            }
        }
    }
}

// ---------------------------------------------------------------------------
// K2: depthwise 3x3 conv. Block = 64 channels of one (b,o).
// Writes vlocI in the aoI image layout so k_av reads vectorized.
// ---------------------------------------------------------------------------
__global__ __launch_bounds__(256) void k_dwconv(
    const u16* __restrict__ vI, const float* __restrict__ wvl,
    const float* __restrict__ TB, u16* __restrict__ vlocI)
{
    __shared__ u16 V[64 * 230];             // 29440 B
    const int tid = threadIdx.x;
    const int sub = blockIdx.x;             // 0..15: o = sub>>1, half = sub&1
    const int b   = blockIdx.y;
    const int o   = sub >> 1;
    const int e0  = (sub & 1) * 64;
    const u16* img = vI + (size_t)(b * 8 + o) * 28672;

    {
        const int quad = tid >> 6, l = tid & 63;
        #pragma unroll
        for (int i = 0; i < 7; i++) {
            v8s u = *(const v8s*)&img[i * 4096 + quad * 1024 + (e0 + l) * 8];
            const u32* ui = (const u32*)&u;
            int m0 = i * 32 + quad * 8;
            u32* dst = (u32*)&V[l * 230 + m0];
            #pragma unroll
            for (int c = 0; c < 4; c++) dst[c] = ui[c];
        }
    }
    __syncthreads();

    const int e = tid & 63, j = tid >> 6;
    const int cg = sub * 64 + e;
    const int y0 = j * 4;
    const int ny = (j == 3) ? 2 : 4;
    float wgt[9];
    #pragma unroll
    for (int k = 0; k < 9; k++) wgt[k] = wvl[cg * 9 + k];
    const float sc = TB[3840 + cg], sh = TB[4864 + cg];
    u32 po[4][7];

    for (int yi = 0; yi < ny; yi++) {
        int y = y0 + yi;
        float a[3][16];
        #pragma unroll
        for (int dy = 0; dy < 3; dy++) {
            int yy = y + dy - 1;
            a[dy][0] = 0.f; a[dy][15] = 0.f;
            if (yy < 0 || yy > 13) {
                #pragma unroll
                for (int x = 1; x < 15; x++) a[dy][x] = 0.f;
            } else {
                const u16* rp = &V[e * 230 + yy * 14];
                #pragma unroll
                for (int c4 = 0; c4 < 7; c4++) {
                    u32 u = *(const u32*)&rp[c4 * 2];
                    a[dy][1 + 2 * c4] = bf2f((u16)(u & 0xffffu));
                    a[dy][2 + 2 * c4] = bf2f((u16)(u >> 16));
                }
            }
        }
        #pragma unroll
        for (int xp = 0; xp < 7; xp++) {
            u32 pk = 0;
            #pragma unroll
            for (int half = 0; half < 2; half++) {
                int x = 2 * xp + half;
                float s = 0.f;
                #pragma unroll
                for (int dy = 0; dy < 3; dy++)
                    #pragma unroll
                    for (int kx = 0; kx < 3; kx++)
                        s += wgt[dy * 3 + kx] * a[dy][x + kx];
                u16 bv = f2bf(s * sc + sh);
                pk |= ((u32)bv) << (16 * half);
            }
            po[yi][xp] = pk;
        }
    }
    __syncthreads();

    for (int yi = 0; yi < ny; yi++) {
        u32* dst = (u32*)&V[e * 196 + (y0 + yi) * 14];
        #pragma unroll
        for (int xp = 0; xp < 7; xp++) dst[xp] = po[yi][xp];
    }
    __syncthreads();

    for (int it = 0; it < 7; it++) {
        int idx = it * 256 + tid;
        if (idx < 1568) {
            int g = idx / 196, n = idx - g * 196;
            v4u lo, hi;
            #pragma unroll
            for (int r = 0; r < 4; r++) lo[r] = V[(g * 8 + r) * 196 + n];
            #pragma unroll
            for (int r = 0; r < 4; r++) hi[r] = V[(g * 8 + 4 + r) * 196 + n];
            u16* dst = vlocI + ((size_t)(b * 2 + (n >> 7)) * 32 + sub * 2 + (g >> 2)) * 4096
                     + (g & 3) * 1024 + (n & 127) * 8;
            *(v4u*)dst = lo;
            *(v4u*)(dst + 4) = hi;
        }
    }
}

// ---------------------------------------------------------------------------
// K3: FUSED attention. Block = (qtile8, b). biasE pre-expanded (coalesced).
// ---------------------------------------------------------------------------
__global__ __launch_bounds__(256) void k_attn(
    const u16* __restrict__ qI, const u16* __restrict__ kI,
    const float* __restrict__ th1w,
    const float* __restrict__ th2w, const float* __restrict__ th2b,
    const float* __restrict__ biasE,
    u16* __restrict__ PbI)
{
    __shared__ u16 Sl[8 * 8 * 228];   // [h][q][m] = 29184 B
    __shared__ float red[64][4];
    __shared__ float invS[64];        // [h*8+q]
    const int tid = threadIdx.x;
    const int w = tid >> 6, lane = tid & 63;
    const int quad = lane >> 4, l16 = lane & 15;
    const int qt = blockIdx.x, b = blockIdx.y;   // qt 0..24
    const int n0 = qt * 8;

    // phase A: wave w -> heads 2w, 2w+1; unrolled so kI loads pipeline
    #pragma unroll
    for (int hh = 0; hh < 2; hh++) {
        int h = w * 2 + hh;
        const u16* qb = qI + (size_t)(b * 8 + h) * 8192;
        const u16* kb = kI + (size_t)(b * 8 + h) * 8192;
        v8s a = *(const v8s*)&qb[(n0 + l16) * 32 + quad * 8];
        #pragma unroll
        for (int mt = 0; mt < 13; mt++) {
            v8s bfr = *(const v8s*)&kb[(mt * 16 + l16) * 32 + quad * 8];
            v4f acc = {};
            acc = __builtin_amdgcn_mfma_f32_16x16x32_bf16(a, bfr, acc, 0, 0, 0);
            if (quad < 2) {
                #pragma unroll
                for (int r = 0; r < 4; r++) {
                    int q = quad * 4 + r;
                    Sl[(h * 8 + q) * 228 + mt * 16 + l16] = f2h(acc[r]);
                }
            }
        }
    }
    __syncthreads();

    // phase B1: thread owns column m; coalesced biasE reads; exp in place fp16
    const int m = tid;
    const bool mact = (m < N_);
    for (int q = 0; q < 8; q++) {
        int n = n0 + q;
        if (mact && n < N_) {
            const float* bE = biasE + (size_t)n * 1568 + m;
            float S[8];
            #pragma unroll
            for (int h = 0; h < 8; h++) S[h] = h2f(Sl[(h * 8 + q) * 228 + m]);
            float E[8];
            #pragma unroll
            for (int o = 0; o < 8; o++) {
                float a = bE[o * 196];
                #pragma unroll
                for (int h = 0; h < 8; h++) a += th1w[o * 8 + h] * S[h];
                E[o] = __expf(a);
            }
            #pragma unroll
            for (int o = 0; o < 8; o++)
                Sl[(o * 8 + q) * 228 + m] = f2h(E[o]);
        }
    }
    __syncthreads();

    // phase B2: 64 rows x 4 threads; vectorized u32 LDS reads
    {
        int r = tid >> 2, quarter = tid & 3;
        int mstart = quarter * 48;
        int cnt = (quarter == 3) ? 26 : 24;
        const u16* rowp = &Sl[r * 228 + mstart];
        float s = 0.f;
        for (int i = 0; i < cnt; i++) {
            u32 u = *(const u32*)&rowp[i * 2];
            s += h2f((u16)(u & 0xffffu)) + h2f((u16)(u >> 16));
        }
        red[r][quarter] = s;
    }
    __syncthreads();
    if (tid < 64)
        invS[tid] = 1.f / (red[tid][0] + red[tid][1] + red[tid][2] + red[tid][3]);
    __syncthreads();

    // phase B3: scale + TH2 in place (bf16)
    for (int q = 0; q < 8; q++) {
        bool valid = mact && (n0 + q < N_);
        float p[8];
        if (valid) {
            float sc[8];
            #pragma unroll
            for (int h = 0; h < 8; h++)
                sc[h] = h2f(Sl[(h * 8 + q) * 228 + m]) * invS[h * 8 + q];
            #pragma unroll
            for (int o = 0; o < 8; o++) {
                float v = th2b[o];
                #pragma unroll
                for (int h = 0; h < 8; h++) v += th2w[o * 8 + h] * sc[h];
                p[o] = v;
            }
        }
        if (m < 224) {
            #pragma unroll
            for (int o = 0; o < 8; o++)
                Sl[(o * 8 + q) * 228 + m] = valid ? f2bf(p[o]) : (u16)0;
        }
    }
    __syncthreads();

    // phase C: copy P -> global image; 16B per lane, 8 lanes per 128B chunk
    const int half = n0 >> 7;
    const int row0 = n0 & 127;
    {
        int lq = lane & 7;          // row within chunk
        int c8 = lane >> 3;         // chunk index within wave-instr (0..7)
        #pragma unroll
        for (int i = 0; i < 7; i++) {
            int ch = w * 56 + i * 8 + c8;               // 0..223
            int o = ch / 28, rem = ch - o * 28;
            int ks = rem >> 2, kq = rem & 3;
            v8s val = *(const v8s*)&Sl[(o * 8 + lq) * 228 + ks * 32 + kq * 8];
            u16* dst = PbI + ((size_t)(b * 8 + o) * 2 + half) * 28672
                     + ks * 4096 + kq * 1024 + (row0 + lq) * 8;
            *(v8s*)dst = val;
        }
    }
}

// ---------------------------------------------------------------------------
// K5: attn @ V (direct core, K=224) + v_local(image) + relu -> aoI image
// ---------------------------------------------------------------------------
__global__ __launch_bounds__(256) void k_av(
    const u16* __restrict__ vI, const u16* __restrict__ PbI,
    const u16* __restrict__ vlocI, u16* __restrict__ aoI)
{
    const int tid = threadIdx.x;
    const int nt = blockIdx.x;
    const int o  = blockIdx.y;
    const int b  = blockIdx.z;
    v4f acc[4][4] = {};
    gemm_direct<7>(vI + (size_t)(b * 8 + o) * 28672,
                   PbI + ((size_t)(b * 8 + o) * 2 + nt) * 28672, acc, tid);

    const int lane = tid & 63, w = tid >> 6;
    const int wm = (w & 1) * 64, wn = (w >> 1) * 64;
    const int quad = lane >> 4, l16 = lane & 15;
    #pragma unroll
    for (int i = 0; i < 4; i++) {
        #pragma unroll
        for (int j = 0; j < 4; j++) {
            int lr = wm + i * 16 + quad * 4;        // e base
            int c0 = o * 128 + lr;                  // global channel base
            int n  = nt * 128 + wn + j * 16 + l16;  // token (0..255)
            size_t ioff = ((size_t)(b * 2 + nt) * 32 + (c0 >> 5)) * 4096
                        + ((c0 >> 3) & 3) * 1024 + (n & 127) * 8 + (c0 & 7);
            v4u lv = *(const v4u*)&vlocI[ioff];
            v4u u;
            #pragma unroll
            for (int r = 0; r < 4; r++) {
                u16 outv = 0;
                if (n < N_) {
                    float val = acc[i][j][r] + bf2f(lv[r]);
                    outv = f2bf(fmaxf(val, 0.f));
                }
                u[r] = outv;
            }
            *(v4u*)&aoI[ioff] = u;
        }
    }
}

// ---------------------------------------------------------------------------
// K6: projection GEMM (direct core, K=1024) + BN -> out fp32
// ---------------------------------------------------------------------------
__global__ __launch_bounds__(256) void k_proj(
    const u16* __restrict__ WpI, const u16* __restrict__ aoI,
    const float* __restrict__ TB, float* __restrict__ out)
{
    const int tid = threadIdx.x;
    const int nt = blockIdx.x;
    const int mt = blockIdx.y;
    const int b  = blockIdx.z;
    v4f acc[4][4] = {};
    gemm_direct<32>(WpI + (size_t)mt * 131072,
                    aoI + ((size_t)b * 2 + nt) * 131072, acc, tid);

    const int lane = tid & 63, w = tid >> 6;
    const int wm = (w & 1) * 64, wn = (w >> 1) * 64;
    const int quad = lane >> 4, l16 = lane & 15;
    #pragma unroll
    for (int i = 0; i < 4; i++) {
        #pragma unroll
        for (int j = 0; j < 4; j++) {
            int p0 = mt * 128 + wm + i * 16 + quad * 4;
            int n  = nt * 128 + wn + j * 16 + l16;
            if (n < N_) {
                v4f s = *(const v4f*)&TB[3072 + p0];
                v4f t = *(const v4f*)&TB[3456 + p0];
                #pragma unroll
                for (int r = 0; r < 4; r++)
                    out[((size_t)b * DIM_ + p0 + r) * N_ + n] = acc[i][j][r] * s[r] + t[r];
            }
        }
    }
}

// ---------------------------------------------------------------------------
extern "C" void kernel_launch(void* const* d_in, const int* in_sizes, int n_in,
                              void* d_out, int out_size, void* d_ws, size_t ws_size,
                              hipStream_t stream)
{
    const float* x    = (const float*)d_in[0];
    const float* wq   = (const float*)d_in[1];
    const float* bq   = (const float*)d_in[2];
    const float* bnq  = (const float*)d_in[3];
    const float* wk   = (const float*)d_in[4];
    const float* bk   = (const float*)d_in[5];
    const float* bnk  = (const float*)d_in[6];
    const float* wv   = (const float*)d_in[7];
    const float* bv   = (const float*)d_in[8];
    const float* bnv  = (const float*)d_in[9];
    const float* wvl  = (const float*)d_in[10];
    const float* bvl  = (const float*)d_in[11];
    const float* bnvl = (const float*)d_in[12];
    const float* th1w = (const float*)d_in[13];
    const float* th1b = (const float*)d_in[14];
    const float* th2w = (const float*)d_in[15];
    const float* th2b = (const float*)d_in[16];
    const float* wp   = (const float*)d_in[17];
    const float* bp   = (const float*)d_in[18];
    const float* bnp  = (const float*)d_in[19];
    const float* ab   = (const float*)d_in[20];
    const int*   bidx = (const int*)d_in[21];
    float* out = (float*)d_out;

    u16* wsb  = (u16*)d_ws;
    u16* WbI  = wsb + WBI_OFF;
    u16* WpI  = wsb + WPI_OFF;
    u16* qI   = wsb + QI_OFF;
    u16* kI   = wsb + KI_OFF;
    u16* vI   = wsb + VI_OFF;
    u16* PbI  = wsb + PBI_OFF;
    u16* vlocI = wsb + VLOC_U16;
    u16* xI   = wsb + TAIL_OFF;   // aliased: xI -> aoI (disjoint lifetimes)
    u16* aoI  = wsb + TAIL_OFF;
    float* TB    = (float*)(wsb + TB_OFF);
    float* abT1  = (float*)(wsb + ABT_OFF);
    float* biasE = (float*)(wsb + BIASE_OFF);

    k_castW<<<dim3(3859), 256, 0, stream>>>(wq, wk, wv, wp, ab, th1w, th1b,
                                            bq, bnq, bk, bnk, bv, bnv, bp, bnp, bvl, bnvl,
                                            WbI, WpI, abT1, TB);
    k_bias<<<dim3((N_ * 8 * N_ + 255) / 256), 256, 0, stream>>>(abT1, bidx, biasE);
    k_castX<<<dim3(4, 6, B_), 256, 0, stream>>>(x, xI);
    k_qkv<<<dim3(2, 12, B_), 256, 0, stream>>>(WbI, xI, TB, qI, kI, vI);
    k_dwconv<<<dim3(16, B_), 256, 0, stream>>>(vI, wvl, TB, vlocI);
    k_attn<<<dim3(25, B_), 256, 0, stream>>>(qI, kI, th1w, th2w, th2b, biasE, PbI);
    k_av<<<dim3(2, HEADS_, B_), 256, 0, stream>>>(vI, PbI, vlocI, aoI);
    k_proj<<<dim3(2, 3, B_), 256, 0, stream>>>(WpI, aoI, TB, out);
}